// Round 1
// baseline (1362.473 us; speedup 1.0000x reference)
//
#include <hip/hip_runtime.h>

static inline int cdiv(long long a, long long b) { return (int)((a + b - 1) / b); }

// ---------------- scatter kernels (segment_sum via atomics) ----------------

__global__ __launch_bounds__(256) void scatter_f2_kernel(
    const int* __restrict__ src, const int* __restrict__ dst,
    const float* __restrict__ ew, const float* __restrict__ x,
    float* __restrict__ agg, int E)
{
    int e = blockIdx.x * blockDim.x + threadIdx.x;
    if (e >= E) return;
    int s = src[e], d = dst[e];
    float w = ew[e];
    atomicAdd(&agg[d * 2 + 0], x[s * 2 + 0] * w);
    atomicAdd(&agg[d * 2 + 1], x[s * 2 + 1] * w);
}

// one (edge,feature) per thread; lanes 0..63 of a wave share one edge
__global__ __launch_bounds__(256) void scatter_f64_kernel(
    const int* __restrict__ src, const int* __restrict__ dst,
    const float* __restrict__ ew, const float* __restrict__ p,
    float* __restrict__ agg, int E)
{
    int t = blockIdx.x * blockDim.x + threadIdx.x;
    int e = t >> 6;
    if (e >= E) return;
    int j = t & 63;
    int s = src[e], d = dst[e];
    float w = ew[e];
    atomicAdd(&agg[(size_t)d * 64 + j], p[(size_t)s * 64 + j] * w);
}

// ---------------- layer 1 (K=2 is tiny: pure elementwise) ----------------

__global__ __launch_bounds__(256) void layer1_kernel(
    const float* __restrict__ x, const float* __restrict__ agg,
    const float* __restrict__ W1rel, const float* __restrict__ W1root,
    const float* __restrict__ b1, float* __restrict__ h1, int N)
{
    int t = blockIdx.x * blockDim.x + threadIdx.x;
    if (t >= N * 128) return;
    int n = t >> 7, j = t & 127;
    float v = b1[j]
        + agg[n * 2 + 0] * W1rel[j] + agg[n * 2 + 1] * W1rel[128 + j]
        + x[n * 2 + 0] * W1root[j] + x[n * 2 + 1] * W1root[128 + j];
    h1[t] = fmaxf(v, 0.f);
}

// ---------------- small-K dense GEMM: out = act(in@W + bias + extra) ------
// W element used: W[(k+woff)*ldw + j]; NOUT in {64,128}; K in {64,128}

template <int K, int NOUT, bool RELU, bool HAS_EXTRA, bool HAS_BIAS>
__global__ __launch_bounds__(256) void gemm_small(
    const float* __restrict__ in, int M,
    const float* __restrict__ W, int ldw, int woff,
    const float* __restrict__ bias,
    const float* __restrict__ extra,
    float* __restrict__ out)
{
    constexpr int CPT = NOUT / 64;   // cols per thread
    __shared__ float sW[K * NOUT];
    __shared__ float sX[4][K];
    const int tid = threadIdx.x;
    const int lane = tid & 63;
    const int wv = tid >> 6;

    for (int idx = tid; idx < K * NOUT; idx += 256) {
        int k = idx / NOUT;
        int j = idx - k * NOUT;
        sW[idx] = W[(size_t)(k + woff) * ldw + j];
    }
    __syncthreads();

    const int ROWS = 32;
    int r0 = blockIdx.x * ROWS;
    for (int rr = wv; rr < ROWS; rr += 4) {
        int r = r0 + rr;
        if (r >= M) break;
        // stage this wave's row in its private LDS slot (same-wave LDS ops
        // are in-order; no block barrier needed)
        #pragma unroll
        for (int kk = lane; kk < K; kk += 64) sX[wv][kk] = in[(size_t)r * K + kk];

        float acc[CPT][4];
        #pragma unroll
        for (int c = 0; c < CPT; c++)
            #pragma unroll
            for (int u = 0; u < 4; u++) acc[c][u] = 0.f;

        #pragma unroll
        for (int k = 0; k < K; k += 4) {
            #pragma unroll
            for (int u = 0; u < 4; u++) {
                float xv = sX[wv][k + u];
                #pragma unroll
                for (int c = 0; c < CPT; c++)
                    acc[c][u] = fmaf(xv, sW[(k + u) * NOUT + c * 64 + lane], acc[c][u]);
            }
        }
        #pragma unroll
        for (int c = 0; c < CPT; c++) {
            float v = (acc[c][0] + acc[c][1]) + (acc[c][2] + acc[c][3]);
            int j = c * 64 + lane;
            if (HAS_EXTRA) v += extra[(size_t)r * NOUT + j];
            if (HAS_BIAS) v += bias[j];
            if (RELU) v = fmaxf(v, 0.f);
            out[(size_t)r * NOUT + j] = v;
        }
    }
}

// ---------------- decoder: one wave per observed edge ----------------

__global__ __launch_bounds__(256) void decoder_kernel(
    const int* __restrict__ src, const int* __restrict__ dst,
    const float* __restrict__ Z1a, const float* __restrict__ Z1b,
    const float* __restrict__ db1, const float* __restrict__ dW2,
    const float* __restrict__ db2, float* __restrict__ pred, int Eobs)
{
    int t = blockIdx.x * blockDim.x + threadIdx.x;
    int e = t >> 6;
    if (e >= Eobs) return;
    int lane = threadIdx.x & 63;
    int s = src[e], d = dst[e];
    float t0 = Z1a[(size_t)s * 128 + lane] + Z1b[(size_t)d * 128 + lane] + db1[lane];
    float t1 = Z1a[(size_t)s * 128 + lane + 64] + Z1b[(size_t)d * 128 + lane + 64] + db1[lane + 64];
    t0 = fmaxf(t0, 0.f);
    t1 = fmaxf(t1, 0.f);
    float acc = t0 * dW2[lane] + t1 * dW2[lane + 64];
    #pragma unroll
    for (int off = 32; off > 0; off >>= 1) acc += __shfl_xor(acc, off, 64);
    if (lane == 0) {
        float pv = acc + db2[0];
        pred[e] = pv;
        pred[e + Eobs] = pv;
    }
}

// ---------------- launch ----------------

extern "C" void kernel_launch(void* const* d_in, const int* in_sizes, int n_in,
                              void* d_out, int out_size, void* d_ws, size_t ws_size,
                              hipStream_t stream)
{
    const float* x     = (const float*)d_in[0];
    const int*   ei    = (const int*)d_in[1];
    const float* ew    = (const float*)d_in[2];
    const float* W1rel = (const float*)d_in[4];
    const float* b1    = (const float*)d_in[5];
    const float* W1rt  = (const float*)d_in[6];
    const float* W2rel = (const float*)d_in[7];
    const float* b2    = (const float*)d_in[8];
    const float* W2rt  = (const float*)d_in[9];
    const float* W3rel = (const float*)d_in[10];
    const float* b3    = (const float*)d_in[11];
    const float* W3rt  = (const float*)d_in[12];
    const float* dW1   = (const float*)d_in[13];
    const float* db1   = (const float*)d_in[14];
    const float* dW2   = (const float*)d_in[15];
    const float* db2   = (const float*)d_in[16];

    const int E    = in_sizes[2];      // 1.6M edges
    const int N    = in_sizes[0] / 2;  // 50000 nodes (x is N x 2)
    const int Eobs = E / 2;            // num_obs
    const int* src = ei;
    const int* dst = ei + E;

    // workspace layout (floats): [agg N*64][h1 N*128][h2 N*64][pbuf N*64]
    float* agg  = (float*)d_ws;
    float* h1   = agg + (size_t)N * 64;
    float* h2   = h1 + (size_t)N * 128;
    float* pbuf = h2 + (size_t)N * 64;
    float* Z1a  = h1;  // h1 dead once h2 exists and z computed
    float* Z1b  = h2;  // spans h2+pbuf (both dead after z)

    float* pred = (float*)d_out;
    float* z    = pred + E;  // second output: (N,64)

    // ---- layer 1: agg in input space (2 feats), then expand to 128 ----
    hipMemsetAsync(agg, 0, (size_t)N * 2 * sizeof(float), stream);
    scatter_f2_kernel<<<cdiv(E, 256), 256, 0, stream>>>(src, dst, ew, x, agg, E);
    layer1_kernel<<<cdiv((long long)N * 128, 256), 256, 0, stream>>>(x, agg, W1rel, W1rt, b1, h1, N);

    // ---- layer 2: p2 = h1@W2_rel; agg = scatter(p2); h2 = relu(h1@W2_root + agg + b2)
    gemm_small<128, 64, false, false, false><<<cdiv(N, 32), 256, 0, stream>>>(
        h1, N, W2rel, 64, 0, nullptr, nullptr, pbuf);
    hipMemsetAsync(agg, 0, (size_t)N * 64 * sizeof(float), stream);
    scatter_f64_kernel<<<cdiv((long long)E * 64, 256), 256, 0, stream>>>(src, dst, ew, pbuf, agg, E);
    gemm_small<128, 64, true, true, true><<<cdiv(N, 32), 256, 0, stream>>>(
        h1, N, W2rt, 64, 0, b2, agg, h2);

    // ---- layer 3: same, no relu, output straight into d_out z-region ----
    gemm_small<64, 64, false, false, false><<<cdiv(N, 32), 256, 0, stream>>>(
        h2, N, W3rel, 64, 0, nullptr, nullptr, pbuf);
    hipMemsetAsync(agg, 0, (size_t)N * 64 * sizeof(float), stream);
    scatter_f64_kernel<<<cdiv((long long)E * 64, 256), 256, 0, stream>>>(src, dst, ew, pbuf, agg, E);
    gemm_small<64, 64, false, true, true><<<cdiv(N, 32), 256, 0, stream>>>(
        h2, N, W3rt, 64, 0, b3, agg, z);

    // ---- decoder: Z1a = z@dec_W1[0:64,:], Z1b = z@dec_W1[64:128,:] ----
    gemm_small<64, 128, false, false, false><<<cdiv(N, 32), 256, 0, stream>>>(
        z, N, dW1, 128, 0, nullptr, nullptr, Z1a);
    gemm_small<64, 128, false, false, false><<<cdiv(N, 32), 256, 0, stream>>>(
        z, N, dW1, 128, 64, nullptr, nullptr, Z1b);
    decoder_kernel<<<cdiv((long long)Eobs * 64, 256), 256, 0, stream>>>(
        src, dst, Z1a, Z1b, db1, dW2, db2, pred, Eobs);
}

// Round 2
// 1016.116 us; speedup vs baseline: 1.3409x; 1.3409x over previous
//
#include <hip/hip_runtime.h>

static inline int cdiv(long long a, long long b) { return (int)((a + b - 1) / b); }

// ---------------- CSR build ----------------

__global__ __launch_bounds__(256) void hist_kernel(
    const int* __restrict__ dst, int* __restrict__ deg, int E)
{
    int e = blockIdx.x * blockDim.x + threadIdx.x;
    if (e < E) atomicAdd(&deg[dst[e]], 1);
}

// single-block exclusive scan of deg[0..N) -> off[0..N)
__global__ __launch_bounds__(1024) void scan_kernel(
    const int* __restrict__ deg, int* __restrict__ off, int N)
{
    __shared__ int sdata[1024];
    __shared__ int srun;
    const int tid = threadIdx.x;
    if (tid == 0) srun = 0;
    __syncthreads();
    for (int base = 0; base < N; base += 1024) {
        int i = base + tid;
        int v = (i < N) ? deg[i] : 0;
        sdata[tid] = v;
        __syncthreads();
        #pragma unroll
        for (int ofs = 1; ofs < 1024; ofs <<= 1) {
            int t = (tid >= ofs) ? sdata[tid - ofs] : 0;
            __syncthreads();
            sdata[tid] += t;
            __syncthreads();
        }
        int run = srun;
        __syncthreads();           // all read srun before thread 1023 rewrites it
        if (tid == 1023) srun = run + sdata[1023];
        if (i < N) off[i] = run + sdata[tid] - v;   // exclusive
        __syncthreads();
    }
}

__global__ __launch_bounds__(256) void fill_csr_kernel(
    const int* __restrict__ src, const int* __restrict__ dst,
    const float* __restrict__ ew, const int* __restrict__ off,
    int* __restrict__ cursor, float2* __restrict__ csr, int E)
{
    int e = blockIdx.x * blockDim.x + threadIdx.x;
    if (e >= E) return;
    int d = dst[e];
    int i = off[d] + atomicAdd(&cursor[d], 1);
    csr[i] = make_float2(__int_as_float(src[e]), ew[e]);
}

// ---------------- gather (replaces atomic scatter): one wave per node ------

__global__ __launch_bounds__(256) void gather_f64_kernel(
    const float2* __restrict__ csr, const int* __restrict__ off,
    const int* __restrict__ deg, const float* __restrict__ p,
    float* __restrict__ agg, int N)
{
    int t = blockIdx.x * blockDim.x + threadIdx.x;
    int n = t >> 6;
    if (n >= N) return;
    int lane = t & 63;
    int beg = off[n], cnt = deg[n];
    float acc = 0.f;
    int i = 0;
    for (; i + 4 <= cnt; i += 4) {
        float2 c0 = csr[beg + i + 0];
        float2 c1 = csr[beg + i + 1];
        float2 c2 = csr[beg + i + 2];
        float2 c3 = csr[beg + i + 3];
        int s0 = __float_as_int(c0.x);
        int s1 = __float_as_int(c1.x);
        int s2 = __float_as_int(c2.x);
        int s3 = __float_as_int(c3.x);
        float v0 = p[(size_t)s0 * 64 + lane];
        float v1 = p[(size_t)s1 * 64 + lane];
        float v2 = p[(size_t)s2 * 64 + lane];
        float v3 = p[(size_t)s3 * 64 + lane];
        acc = fmaf(c0.y, v0, acc);
        acc = fmaf(c1.y, v1, acc);
        acc = fmaf(c2.y, v2, acc);
        acc = fmaf(c3.y, v3, acc);
    }
    for (; i < cnt; i++) {
        float2 c = csr[beg + i];
        acc = fmaf(c.y, p[(size_t)__float_as_int(c.x) * 64 + lane], acc);
    }
    agg[(size_t)n * 64 + lane] = acc;
}

// ---------------- fallback atomic scatters (if ws too small) ----------------

__global__ __launch_bounds__(256) void scatter_f64_kernel(
    const int* __restrict__ src, const int* __restrict__ dst,
    const float* __restrict__ ew, const float* __restrict__ p,
    float* __restrict__ agg, int E)
{
    int t = blockIdx.x * blockDim.x + threadIdx.x;
    int e = t >> 6;
    if (e >= E) return;
    int j = t & 63;
    int s = src[e], d = dst[e];
    float w = ew[e];
    atomicAdd(&agg[(size_t)d * 64 + j], p[(size_t)s * 64 + j] * w);
}

__global__ __launch_bounds__(256) void scatter_f2_kernel(
    const int* __restrict__ src, const int* __restrict__ dst,
    const float* __restrict__ ew, const float* __restrict__ x,
    float* __restrict__ agg, int E)
{
    int e = blockIdx.x * blockDim.x + threadIdx.x;
    if (e >= E) return;
    int s = src[e], d = dst[e];
    float w = ew[e];
    atomicAdd(&agg[d * 2 + 0], x[s * 2 + 0] * w);
    atomicAdd(&agg[d * 2 + 1], x[s * 2 + 1] * w);
}

// ---------------- layer 1 (K=2 is tiny: pure elementwise) ----------------

__global__ __launch_bounds__(256) void layer1_kernel(
    const float* __restrict__ x, const float* __restrict__ agg,
    const float* __restrict__ W1rel, const float* __restrict__ W1root,
    const float* __restrict__ b1, float* __restrict__ h1, int N)
{
    int t = blockIdx.x * blockDim.x + threadIdx.x;
    if (t >= N * 128) return;
    int n = t >> 7, j = t & 127;
    float v = b1[j]
        + agg[n * 2 + 0] * W1rel[j] + agg[n * 2 + 1] * W1rel[128 + j]
        + x[n * 2 + 0] * W1root[j] + x[n * 2 + 1] * W1root[128 + j];
    h1[t] = fmaxf(v, 0.f);
}

// ---------------- small-K dense GEMM: out = act(in@W + bias + extra) ------

template <int K, int NOUT, bool RELU, bool HAS_EXTRA, bool HAS_BIAS>
__global__ __launch_bounds__(256) void gemm_small(
    const float* __restrict__ in, int M,
    const float* __restrict__ W, int ldw, int woff,
    const float* __restrict__ bias,
    const float* __restrict__ extra,
    float* __restrict__ out)
{
    constexpr int CPT = NOUT / 64;   // cols per thread
    __shared__ float sW[K * NOUT];
    __shared__ float sX[4][K];
    const int tid = threadIdx.x;
    const int lane = tid & 63;
    const int wv = tid >> 6;

    for (int idx = tid; idx < K * NOUT; idx += 256) {
        int k = idx / NOUT;
        int j = idx - k * NOUT;
        sW[idx] = W[(size_t)(k + woff) * ldw + j];
    }
    __syncthreads();

    const int ROWS = 32;
    int r0 = blockIdx.x * ROWS;
    for (int rr = wv; rr < ROWS; rr += 4) {
        int r = r0 + rr;
        if (r >= M) break;
        #pragma unroll
        for (int kk = lane; kk < K; kk += 64) sX[wv][kk] = in[(size_t)r * K + kk];

        float acc[CPT][4];
        #pragma unroll
        for (int c = 0; c < CPT; c++)
            #pragma unroll
            for (int u = 0; u < 4; u++) acc[c][u] = 0.f;

        #pragma unroll
        for (int k = 0; k < K; k += 4) {
            #pragma unroll
            for (int u = 0; u < 4; u++) {
                float xv = sX[wv][k + u];
                #pragma unroll
                for (int c = 0; c < CPT; c++)
                    acc[c][u] = fmaf(xv, sW[(k + u) * NOUT + c * 64 + lane], acc[c][u]);
            }
        }
        #pragma unroll
        for (int c = 0; c < CPT; c++) {
            float v = (acc[c][0] + acc[c][1]) + (acc[c][2] + acc[c][3]);
            int j = c * 64 + lane;
            if (HAS_EXTRA) v += extra[(size_t)r * NOUT + j];
            if (HAS_BIAS) v += bias[j];
            if (RELU) v = fmaxf(v, 0.f);
            out[(size_t)r * NOUT + j] = v;
        }
    }
}

// ---------------- decoder: one wave per observed edge ----------------

__global__ __launch_bounds__(256) void decoder_kernel(
    const int* __restrict__ src, const int* __restrict__ dst,
    const float* __restrict__ Z1a, const float* __restrict__ Z1b,
    const float* __restrict__ db1, const float* __restrict__ dW2,
    const float* __restrict__ db2, float* __restrict__ pred, int Eobs)
{
    int t = blockIdx.x * blockDim.x + threadIdx.x;
    int e = t >> 6;
    if (e >= Eobs) return;
    int lane = threadIdx.x & 63;
    int s = src[e], d = dst[e];
    float t0 = Z1a[(size_t)s * 128 + lane] + Z1b[(size_t)d * 128 + lane] + db1[lane];
    float t1 = Z1a[(size_t)s * 128 + lane + 64] + Z1b[(size_t)d * 128 + lane + 64] + db1[lane + 64];
    t0 = fmaxf(t0, 0.f);
    t1 = fmaxf(t1, 0.f);
    float acc = t0 * dW2[lane] + t1 * dW2[lane + 64];
    #pragma unroll
    for (int off = 32; off > 0; off >>= 1) acc += __shfl_xor(acc, off, 64);
    if (lane == 0) {
        float pv = acc + db2[0];
        pred[e] = pv;
        pred[e + Eobs] = pv;
    }
}

// ---------------- launch ----------------

extern "C" void kernel_launch(void* const* d_in, const int* in_sizes, int n_in,
                              void* d_out, int out_size, void* d_ws, size_t ws_size,
                              hipStream_t stream)
{
    const float* x     = (const float*)d_in[0];
    const int*   ei    = (const int*)d_in[1];
    const float* ew    = (const float*)d_in[2];
    const float* W1rel = (const float*)d_in[4];
    const float* b1    = (const float*)d_in[5];
    const float* W1rt  = (const float*)d_in[6];
    const float* W2rel = (const float*)d_in[7];
    const float* b2    = (const float*)d_in[8];
    const float* W2rt  = (const float*)d_in[9];
    const float* W3rel = (const float*)d_in[10];
    const float* b3    = (const float*)d_in[11];
    const float* W3rt  = (const float*)d_in[12];
    const float* dW1   = (const float*)d_in[13];
    const float* db1   = (const float*)d_in[14];
    const float* dW2   = (const float*)d_in[15];
    const float* db2   = (const float*)d_in[16];

    const int E    = in_sizes[2];      // 1.6M edges
    const int N    = in_sizes[0] / 2;  // 50000 nodes
    const int Eobs = E / 2;
    const int* src = ei;
    const int* dst = ei + E;

    // workspace layout (floats):
    // [agg N*64][h1 N*128][h2 N*64][pbuf N*64][deg N][off N][cursor N][csr E*2]
    float* agg  = (float*)d_ws;
    float* h1   = agg + (size_t)N * 64;
    float* h2   = h1 + (size_t)N * 128;
    float* pbuf = h2 + (size_t)N * 64;
    int*   deg  = (int*)(pbuf + (size_t)N * 64);
    int*   off  = deg + N;
    int*   curs = off + N;
    float2* csr = (float2*)(curs + N);

    size_t need = ((size_t)N * 320 + (size_t)N * 3) * 4 + (size_t)E * 8;
    const bool use_csr = (ws_size >= need);

    float* Z1a  = h1;   // h1 dead after layer-2 root gemm
    float* Z1b  = h2;   // h2+pbuf dead after layer-3

    float* pred = (float*)d_out;
    float* z    = pred + E;

    // ---- CSR build (once, reused for layer-2 and layer-3 aggregation) ----
    if (use_csr) {
        hipMemsetAsync(deg, 0, (size_t)N * 2 * sizeof(int), stream);   // deg + off? no: deg only; off fully written
        hipMemsetAsync(curs, 0, (size_t)N * sizeof(int), stream);
        hist_kernel<<<cdiv(E, 256), 256, 0, stream>>>(dst, deg, E);
        scan_kernel<<<1, 1024, 0, stream>>>(deg, off, N);
        fill_csr_kernel<<<cdiv(E, 256), 256, 0, stream>>>(src, dst, ew, off, curs, csr, E);
    }

    // ---- layer 1: agg in input space (2 feats), then expand to 128 ----
    hipMemsetAsync(agg, 0, (size_t)N * 2 * sizeof(float), stream);
    scatter_f2_kernel<<<cdiv(E, 256), 256, 0, stream>>>(src, dst, ew, x, agg, E);
    layer1_kernel<<<cdiv((long long)N * 128, 256), 256, 0, stream>>>(x, agg, W1rel, W1rt, b1, h1, N);

    // ---- layer 2 ----
    gemm_small<128, 64, false, false, false><<<cdiv(N, 32), 256, 0, stream>>>(
        h1, N, W2rel, 64, 0, nullptr, nullptr, pbuf);
    if (use_csr) {
        gather_f64_kernel<<<cdiv((long long)N * 64, 256), 256, 0, stream>>>(csr, off, deg, pbuf, agg, N);
    } else {
        hipMemsetAsync(agg, 0, (size_t)N * 64 * sizeof(float), stream);
        scatter_f64_kernel<<<cdiv((long long)E * 64, 256), 256, 0, stream>>>(src, dst, ew, pbuf, agg, E);
    }
    gemm_small<128, 64, true, true, true><<<cdiv(N, 32), 256, 0, stream>>>(
        h1, N, W2rt, 64, 0, b2, agg, h2);

    // ---- layer 3 ----
    gemm_small<64, 64, false, false, false><<<cdiv(N, 32), 256, 0, stream>>>(
        h2, N, W3rel, 64, 0, nullptr, nullptr, pbuf);
    if (use_csr) {
        gather_f64_kernel<<<cdiv((long long)N * 64, 256), 256, 0, stream>>>(csr, off, deg, pbuf, agg, N);
    } else {
        hipMemsetAsync(agg, 0, (size_t)N * 64 * sizeof(float), stream);
        scatter_f64_kernel<<<cdiv((long long)E * 64, 256), 256, 0, stream>>>(src, dst, ew, pbuf, agg, E);
    }
    gemm_small<64, 64, false, true, true><<<cdiv(N, 32), 256, 0, stream>>>(
        h2, N, W3rt, 64, 0, b3, agg, z);

    // ---- decoder ----
    gemm_small<64, 128, false, false, false><<<cdiv(N, 32), 256, 0, stream>>>(
        z, N, dW1, 128, 0, nullptr, nullptr, Z1a);
    gemm_small<64, 128, false, false, false><<<cdiv(N, 32), 256, 0, stream>>>(
        z, N, dW1, 128, 64, nullptr, nullptr, Z1b);
    decoder_kernel<<<cdiv((long long)Eobs * 64, 256), 256, 0, stream>>>(
        src, dst, Z1a, Z1b, db1, dW2, db2, pred, Eobs);
}

// Round 3
// 762.365 us; speedup vs baseline: 1.7872x; 1.3328x over previous
//
#include <hip/hip_runtime.h>
#include <hip/hip_bf16.h>

static inline int cdiv(long long a, long long b) { return (int)((a + b - 1) / b); }

// ---------------- CSR build ----------------

__global__ __launch_bounds__(256) void hist_kernel(
    const int* __restrict__ dst, int* __restrict__ deg, int E)
{
    int e = blockIdx.x * blockDim.x + threadIdx.x;
    if (e < E) atomicAdd(&deg[dst[e]], 1);
}

// per-block exclusive scan chunk; block totals to partials (if non-null)
__global__ __launch_bounds__(1024) void scan_block_kernel(
    const int* __restrict__ in, int* __restrict__ out,
    int* __restrict__ partials, int N)
{
    __shared__ int sdata[1024];
    const int tid = threadIdx.x;
    const int i = blockIdx.x * 1024 + tid;
    int v = (i < N) ? in[i] : 0;
    sdata[tid] = v;
    __syncthreads();
    #pragma unroll
    for (int ofs = 1; ofs < 1024; ofs <<= 1) {
        int t = (tid >= ofs) ? sdata[tid - ofs] : 0;
        __syncthreads();
        sdata[tid] += t;
        __syncthreads();
    }
    if (i < N) out[i] = sdata[tid] - v;          // exclusive within block
    if (partials && tid == 1023) partials[blockIdx.x] = sdata[1023];
}

__global__ __launch_bounds__(1024) void scan_add_kernel(
    int* __restrict__ off, const int* __restrict__ blockoff, int N)
{
    int i = blockIdx.x * blockDim.x + threadIdx.x;
    if (i < N) off[i] += blockoff[i >> 10];
}

__global__ __launch_bounds__(256) void fill_csr_kernel(
    const int* __restrict__ src, const int* __restrict__ dst,
    const float* __restrict__ ew, const int* __restrict__ off,
    int* __restrict__ cursor, float2* __restrict__ csr, int E)
{
    int e = blockIdx.x * blockDim.x + threadIdx.x;
    if (e >= E) return;
    int d = dst[e];
    int i = off[d] + atomicAdd(&cursor[d], 1);
    csr[i] = make_float2(__int_as_float(src[e]), ew[e]);
}

// ---------------- fused layer 1: CSR gather (2 feats) + expand to 128 -----

__global__ __launch_bounds__(256) void layer1_fused_kernel(
    const float2* __restrict__ x2, const float2* __restrict__ csr,
    const int* __restrict__ off, const int* __restrict__ deg,
    const float* __restrict__ W1rel, const float* __restrict__ W1rt,
    const float* __restrict__ b1, float* __restrict__ h1, int N)
{
    int t = blockIdx.x * blockDim.x + threadIdx.x;
    int n = t >> 6;
    if (n >= N) return;
    int lane = t & 63;
    int beg = off[n], cnt = deg[n];
    float a0 = 0.f, a1 = 0.f;
    for (int i = lane; i < cnt; i += 64) {
        float2 c = csr[beg + i];
        float2 xs = x2[__float_as_int(c.x)];
        a0 = fmaf(c.y, xs.x, a0);
        a1 = fmaf(c.y, xs.y, a1);
    }
    #pragma unroll
    for (int o = 32; o > 0; o >>= 1) {
        a0 += __shfl_xor(a0, o, 64);
        a1 += __shfl_xor(a1, o, 64);
    }
    float2 xn = x2[n];
    float v0 = b1[lane] + a0 * W1rel[lane] + a1 * W1rel[128 + lane]
             + xn.x * W1rt[lane] + xn.y * W1rt[128 + lane];
    float v1 = b1[64 + lane] + a0 * W1rel[64 + lane] + a1 * W1rel[192 + lane]
             + xn.x * W1rt[64 + lane] + xn.y * W1rt[192 + lane];
    h1[(size_t)n * 128 + lane]      = fmaxf(v0, 0.f);
    h1[(size_t)n * 128 + 64 + lane] = fmaxf(v1, 0.f);
}

// ---------------- gather aggregation: one wave per node ----------------

__global__ __launch_bounds__(256) void gather_f64_kernel(
    const float2* __restrict__ csr, const int* __restrict__ off,
    const int* __restrict__ deg, const float* __restrict__ p,
    float* __restrict__ agg, int N)
{
    int t = blockIdx.x * blockDim.x + threadIdx.x;
    int n = t >> 6;
    if (n >= N) return;
    int lane = t & 63;
    int beg = off[n], cnt = deg[n];
    float acc = 0.f;
    int i = 0;
    for (; i + 4 <= cnt; i += 4) {
        float2 c0 = csr[beg + i + 0];
        float2 c1 = csr[beg + i + 1];
        float2 c2 = csr[beg + i + 2];
        float2 c3 = csr[beg + i + 3];
        float v0 = p[(size_t)__float_as_int(c0.x) * 64 + lane];
        float v1 = p[(size_t)__float_as_int(c1.x) * 64 + lane];
        float v2 = p[(size_t)__float_as_int(c2.x) * 64 + lane];
        float v3 = p[(size_t)__float_as_int(c3.x) * 64 + lane];
        acc = fmaf(c0.y, v0, acc);
        acc = fmaf(c1.y, v1, acc);
        acc = fmaf(c2.y, v2, acc);
        acc = fmaf(c3.y, v3, acc);
    }
    for (; i < cnt; i++) {
        float2 c = csr[beg + i];
        acc = fmaf(c.y, p[(size_t)__float_as_int(c.x) * 64 + lane], acc);
    }
    agg[(size_t)n * 64 + lane] = acc;
}

// ---------------- fallback atomic path (if ws too small) ----------------

__global__ __launch_bounds__(256) void scatter_f64_kernel(
    const int* __restrict__ src, const int* __restrict__ dst,
    const float* __restrict__ ew, const float* __restrict__ p,
    float* __restrict__ agg, int E)
{
    int t = blockIdx.x * blockDim.x + threadIdx.x;
    int e = t >> 6;
    if (e >= E) return;
    int j = t & 63;
    atomicAdd(&agg[(size_t)dst[e] * 64 + j], p[(size_t)src[e] * 64 + j] * ew[e]);
}

__global__ __launch_bounds__(256) void scatter_f2_kernel(
    const int* __restrict__ src, const int* __restrict__ dst,
    const float* __restrict__ ew, const float* __restrict__ x,
    float* __restrict__ agg, int E)
{
    int e = blockIdx.x * blockDim.x + threadIdx.x;
    if (e >= E) return;
    int s = src[e], d = dst[e];
    float w = ew[e];
    atomicAdd(&agg[d * 2 + 0], x[s * 2 + 0] * w);
    atomicAdd(&agg[d * 2 + 1], x[s * 2 + 1] * w);
}

__global__ __launch_bounds__(256) void layer1_kernel(
    const float* __restrict__ x, const float* __restrict__ agg,
    const float* __restrict__ W1rel, const float* __restrict__ W1root,
    const float* __restrict__ b1, float* __restrict__ h1, int N)
{
    int t = blockIdx.x * blockDim.x + threadIdx.x;
    if (t >= N * 128) return;
    int n = t >> 7, j = t & 127;
    float v = b1[j]
        + agg[n * 2 + 0] * W1rel[j] + agg[n * 2 + 1] * W1rel[128 + j]
        + x[n * 2 + 0] * W1root[j] + x[n * 2 + 1] * W1root[128 + j];
    h1[t] = fmaxf(v, 0.f);
}

// ---------------- small-K dense GEMM: out = act(in@W + bias + extra) ------

template <int K, int NOUT, bool RELU, bool HAS_EXTRA, bool HAS_BIAS, bool OUT_BF16>
__global__ __launch_bounds__(256) void gemm_small(
    const float* __restrict__ in, int M,
    const float* __restrict__ W, int ldw, int woff,
    const float* __restrict__ bias,
    const float* __restrict__ extra,
    void* __restrict__ out_)
{
    constexpr int CPT = NOUT / 64;
    __shared__ float sW[K * NOUT];
    __shared__ float sX[4][K];
    const int tid = threadIdx.x;
    const int lane = tid & 63;
    const int wv = tid >> 6;

    for (int idx = tid; idx < K * NOUT; idx += 256) {
        int k = idx / NOUT;
        int j = idx - k * NOUT;
        sW[idx] = W[(size_t)(k + woff) * ldw + j];
    }
    __syncthreads();

    const int ROWS = 32;
    int r0 = blockIdx.x * ROWS;
    for (int rr = wv; rr < ROWS; rr += 4) {
        int r = r0 + rr;
        if (r >= M) break;
        #pragma unroll
        for (int kk = lane; kk < K; kk += 64) sX[wv][kk] = in[(size_t)r * K + kk];

        float acc[CPT][4];
        #pragma unroll
        for (int c = 0; c < CPT; c++)
            #pragma unroll
            for (int u = 0; u < 4; u++) acc[c][u] = 0.f;

        #pragma unroll
        for (int k = 0; k < K; k += 4) {
            #pragma unroll
            for (int u = 0; u < 4; u++) {
                float xv = sX[wv][k + u];
                #pragma unroll
                for (int c = 0; c < CPT; c++)
                    acc[c][u] = fmaf(xv, sW[(k + u) * NOUT + c * 64 + lane], acc[c][u]);
            }
        }
        #pragma unroll
        for (int c = 0; c < CPT; c++) {
            float v = (acc[c][0] + acc[c][1]) + (acc[c][2] + acc[c][3]);
            int j = c * 64 + lane;
            if (HAS_EXTRA) v += extra[(size_t)r * NOUT + j];
            if (HAS_BIAS) v += bias[j];
            if (RELU) v = fmaxf(v, 0.f);
            if (OUT_BF16)
                ((__hip_bfloat16*)out_)[(size_t)r * NOUT + j] = __float2bfloat16(v);
            else
                ((float*)out_)[(size_t)r * NOUT + j] = v;
        }
    }
}

// ---------------- decoder: one wave per observed edge, bf16 tables --------

__global__ __launch_bounds__(256) void decoder_bf16_kernel(
    const int* __restrict__ src, const int* __restrict__ dst,
    const __hip_bfloat162* __restrict__ Z1a, const __hip_bfloat162* __restrict__ Z1b,
    const float* __restrict__ db1, const float* __restrict__ dW2,
    const float* __restrict__ db2, float* __restrict__ pred, int Eobs)
{
    int t = blockIdx.x * blockDim.x + threadIdx.x;
    int e = t >> 6;
    if (e >= Eobs) return;
    int lane = t & 63;
    int s = src[e], d = dst[e];
    float2 a = __bfloat1622float2(Z1a[(size_t)s * 64 + lane]);
    float2 b = __bfloat1622float2(Z1b[(size_t)d * 64 + lane]);
    float v0 = fmaxf(a.x + b.x + db1[2 * lane], 0.f);
    float v1 = fmaxf(a.y + b.y + db1[2 * lane + 1], 0.f);
    float acc = v0 * dW2[2 * lane] + v1 * dW2[2 * lane + 1];
    #pragma unroll
    for (int o = 32; o > 0; o >>= 1) acc += __shfl_xor(acc, o, 64);
    if (lane == 0) {
        float pv = acc + db2[0];
        pred[e] = pv;
        pred[e + Eobs] = pv;
    }
}

__global__ __launch_bounds__(256) void decoder_kernel(
    const int* __restrict__ src, const int* __restrict__ dst,
    const float* __restrict__ Z1a, const float* __restrict__ Z1b,
    const float* __restrict__ db1, const float* __restrict__ dW2,
    const float* __restrict__ db2, float* __restrict__ pred, int Eobs)
{
    int t = blockIdx.x * blockDim.x + threadIdx.x;
    int e = t >> 6;
    if (e >= Eobs) return;
    int lane = threadIdx.x & 63;
    int s = src[e], d = dst[e];
    float t0 = Z1a[(size_t)s * 128 + lane] + Z1b[(size_t)d * 128 + lane] + db1[lane];
    float t1 = Z1a[(size_t)s * 128 + lane + 64] + Z1b[(size_t)d * 128 + lane + 64] + db1[lane + 64];
    t0 = fmaxf(t0, 0.f);
    t1 = fmaxf(t1, 0.f);
    float acc = t0 * dW2[lane] + t1 * dW2[lane + 64];
    #pragma unroll
    for (int off = 32; off > 0; off >>= 1) acc += __shfl_xor(acc, off, 64);
    if (lane == 0) {
        float pv = acc + db2[0];
        pred[e] = pv;
        pred[e + Eobs] = pv;
    }
}

// ---------------- launch ----------------

extern "C" void kernel_launch(void* const* d_in, const int* in_sizes, int n_in,
                              void* d_out, int out_size, void* d_ws, size_t ws_size,
                              hipStream_t stream)
{
    const float* x     = (const float*)d_in[0];
    const int*   ei    = (const int*)d_in[1];
    const float* ew    = (const float*)d_in[2];
    const float* W1rel = (const float*)d_in[4];
    const float* b1    = (const float*)d_in[5];
    const float* W1rt  = (const float*)d_in[6];
    const float* W2rel = (const float*)d_in[7];
    const float* b2    = (const float*)d_in[8];
    const float* W2rt  = (const float*)d_in[9];
    const float* W3rel = (const float*)d_in[10];
    const float* b3    = (const float*)d_in[11];
    const float* W3rt  = (const float*)d_in[12];
    const float* dW1   = (const float*)d_in[13];
    const float* db1   = (const float*)d_in[14];
    const float* dW2   = (const float*)d_in[15];
    const float* db2   = (const float*)d_in[16];

    const int E    = in_sizes[2];
    const int N    = in_sizes[0] / 2;
    const int Eobs = E / 2;
    const int* src = ei;
    const int* dst = ei + E;

    // ws layout (floats):
    // [agg N*64][h1 N*128][h2 N*64][pbuf N*64][deg N][curs N][off N][p1 1024][p2 1024][csr E*2]
    float* agg  = (float*)d_ws;
    float* h1   = agg + (size_t)N * 64;
    float* h2   = h1 + (size_t)N * 128;
    float* pbuf = h2 + (size_t)N * 64;
    int*   deg  = (int*)(pbuf + (size_t)N * 64);
    int*   curs = deg + N;          // adjacent to deg: one memset covers both
    int*   off  = curs + N;
    int*   par1 = off + N;
    int*   par2 = par1 + 1024;
    float2* csr = (float2*)(par2 + 1024);

    size_t need = ((size_t)N * 320 + (size_t)N * 3 + 2048) * 4 + (size_t)E * 8;
    const bool use_csr = (ws_size >= need);

    float* pred = (float*)d_out;
    float* z    = pred + E;
    __hip_bfloat16* Z1a16 = (__hip_bfloat16*)h1;   // h1 dead after layer-2
    __hip_bfloat16* Z1b16 = (__hip_bfloat16*)h2;   // h2 dead after layer-3

    const int nscan = cdiv(N, 1024);

    if (use_csr) {
        // ---- CSR build (reused for all three aggregations) ----
        hipMemsetAsync(deg, 0, (size_t)N * 2 * sizeof(int), stream);  // deg + curs
        hist_kernel<<<cdiv(E, 256), 256, 0, stream>>>(dst, deg, E);
        scan_block_kernel<<<nscan, 1024, 0, stream>>>(deg, off, par1, N);
        scan_block_kernel<<<1, 1024, 0, stream>>>(par1, par2, nullptr, nscan);
        scan_add_kernel<<<cdiv(N, 1024), 1024, 0, stream>>>(off, par2, N);
        fill_csr_kernel<<<cdiv(E, 256), 256, 0, stream>>>(src, dst, ew, off, curs, csr, E);

        // ---- layer 1 (fused CSR gather + expansion) ----
        layer1_fused_kernel<<<cdiv((long long)N * 64, 256), 256, 0, stream>>>(
            (const float2*)x, csr, off, deg, W1rel, W1rt, b1, h1, N);

        // ---- layer 2 ----
        gemm_small<128, 64, false, false, false, false><<<cdiv(N, 32), 256, 0, stream>>>(
            h1, N, W2rel, 64, 0, nullptr, nullptr, pbuf);
        gather_f64_kernel<<<cdiv((long long)N * 64, 256), 256, 0, stream>>>(csr, off, deg, pbuf, agg, N);
        gemm_small<128, 64, true, true, true, false><<<cdiv(N, 32), 256, 0, stream>>>(
            h1, N, W2rt, 64, 0, b2, agg, h2);

        // ---- layer 3 ----
        gemm_small<64, 64, false, false, false, false><<<cdiv(N, 32), 256, 0, stream>>>(
            h2, N, W3rel, 64, 0, nullptr, nullptr, pbuf);
        gather_f64_kernel<<<cdiv((long long)N * 64, 256), 256, 0, stream>>>(csr, off, deg, pbuf, agg, N);
        gemm_small<64, 64, false, true, true, false><<<cdiv(N, 32), 256, 0, stream>>>(
            h2, N, W3rt, 64, 0, b3, agg, z);

        // ---- decoder (bf16 tables) ----
        gemm_small<64, 128, false, false, false, true><<<cdiv(N, 32), 256, 0, stream>>>(
            z, N, dW1, 128, 0, nullptr, nullptr, Z1a16);
        gemm_small<64, 128, false, false, false, true><<<cdiv(N, 32), 256, 0, stream>>>(
            z, N, dW1, 128, 64, nullptr, nullptr, Z1b16);
        decoder_bf16_kernel<<<cdiv((long long)Eobs * 64, 256), 256, 0, stream>>>(
            src, dst, (const __hip_bfloat162*)Z1a16, (const __hip_bfloat162*)Z1b16,
            db1, dW2, db2, pred, Eobs);
    } else {
        // ---- fallback: atomic scatter path ----
        float* Z1a = h1;
        float* Z1b = h2;
        hipMemsetAsync(agg, 0, (size_t)N * 2 * sizeof(float), stream);
        scatter_f2_kernel<<<cdiv(E, 256), 256, 0, stream>>>(src, dst, ew, x, agg, E);
        layer1_kernel<<<cdiv((long long)N * 128, 256), 256, 0, stream>>>(x, agg, W1rel, W1rt, b1, h1, N);

        gemm_small<128, 64, false, false, false, false><<<cdiv(N, 32), 256, 0, stream>>>(
            h1, N, W2rel, 64, 0, nullptr, nullptr, pbuf);
        hipMemsetAsync(agg, 0, (size_t)N * 64 * sizeof(float), stream);
        scatter_f64_kernel<<<cdiv((long long)E * 64, 256), 256, 0, stream>>>(src, dst, ew, pbuf, agg, E);
        gemm_small<128, 64, true, true, true, false><<<cdiv(N, 32), 256, 0, stream>>>(
            h1, N, W2rt, 64, 0, b2, agg, h2);

        gemm_small<64, 64, false, false, false, false><<<cdiv(N, 32), 256, 0, stream>>>(
            h2, N, W3rel, 64, 0, nullptr, nullptr, pbuf);
        hipMemsetAsync(agg, 0, (size_t)N * 64 * sizeof(float), stream);
        scatter_f64_kernel<<<cdiv((long long)E * 64, 256), 256, 0, stream>>>(src, dst, ew, pbuf, agg, E);
        gemm_small<64, 64, false, true, true, false><<<cdiv(N, 32), 256, 0, stream>>>(
            h2, N, W3rt, 64, 0, b3, agg, z);

        gemm_small<64, 128, false, false, false, false><<<cdiv(N, 32), 256, 0, stream>>>(
            z, N, dW1, 128, 0, nullptr, nullptr, Z1a);
        gemm_small<64, 128, false, false, false, false><<<cdiv(N, 32), 256, 0, stream>>>(
            z, N, dW1, 128, 64, nullptr, nullptr, Z1b);
        decoder_kernel<<<cdiv((long long)Eobs * 64, 256), 256, 0, stream>>>(
            src, dst, Z1a, Z1b, db1, dW2, db2, pred, Eobs);
    }
}

// Round 4
// 656.268 us; speedup vs baseline: 2.0761x; 1.1617x over previous
//
#include <hip/hip_runtime.h>
#include <hip/hip_bf16.h>

static inline int cdiv(long long a, long long b) { return (int)((a + b - 1) / b); }

__device__ inline float bf_lo(unsigned u) { return __uint_as_float(u << 16); }
__device__ inline float bf_hi(unsigned u) { return __uint_as_float(u & 0xffff0000u); }

// ---------------- CSR build ----------------

__global__ __launch_bounds__(256) void hist_kernel(
    const int* __restrict__ dst, int* __restrict__ deg, int E)
{
    int e = blockIdx.x * blockDim.x + threadIdx.x;
    if (e < E) atomicAdd(&deg[dst[e]], 1);
}

__global__ __launch_bounds__(1024) void scan_block_kernel(
    const int* __restrict__ in, int* __restrict__ out,
    int* __restrict__ partials, int N)
{
    __shared__ int sdata[1024];
    const int tid = threadIdx.x;
    const int i = blockIdx.x * 1024 + tid;
    int v = (i < N) ? in[i] : 0;
    sdata[tid] = v;
    __syncthreads();
    #pragma unroll
    for (int ofs = 1; ofs < 1024; ofs <<= 1) {
        int t = (tid >= ofs) ? sdata[tid - ofs] : 0;
        __syncthreads();
        sdata[tid] += t;
        __syncthreads();
    }
    if (i < N) out[i] = sdata[tid] - v;
    if (partials && tid == 1023) partials[blockIdx.x] = sdata[1023];
}

__global__ __launch_bounds__(1024) void scan_add_kernel(
    int* __restrict__ off, const int* __restrict__ blockoff, int N)
{
    int i = blockIdx.x * blockDim.x + threadIdx.x;
    if (i < N) off[i] += blockoff[i >> 10];
}

__global__ __launch_bounds__(256) void fill_csr_kernel(
    const int* __restrict__ src, const int* __restrict__ dst,
    const float* __restrict__ ew, const int* __restrict__ off,
    int* __restrict__ cursor, float2* __restrict__ csr, int E)
{
    int e = blockIdx.x * blockDim.x + threadIdx.x;
    if (e >= E) return;
    int d = dst[e];
    int i = off[d] + atomicAdd(&cursor[d], 1);
    csr[i] = make_float2(__int_as_float(src[e]), ew[e]);
}

// ---------------- fused layer 1: CSR gather (2 feats) + expand to 128 -----

__global__ __launch_bounds__(256) void layer1_fused_kernel(
    const float2* __restrict__ x2, const float2* __restrict__ csr,
    const int* __restrict__ off, const int* __restrict__ deg,
    const float* __restrict__ W1rel, const float* __restrict__ W1rt,
    const float* __restrict__ b1, float* __restrict__ h1, int N)
{
    int t = blockIdx.x * blockDim.x + threadIdx.x;
    int n = t >> 6;
    if (n >= N) return;
    int lane = t & 63;
    int beg = off[n], cnt = deg[n];
    float a0 = 0.f, a1 = 0.f;
    for (int i = lane; i < cnt; i += 64) {
        float2 c = csr[beg + i];
        float2 xs = x2[__float_as_int(c.x)];
        a0 = fmaf(c.y, xs.x, a0);
        a1 = fmaf(c.y, xs.y, a1);
    }
    #pragma unroll
    for (int o = 32; o > 0; o >>= 1) {
        a0 += __shfl_xor(a0, o, 64);
        a1 += __shfl_xor(a1, o, 64);
    }
    float2 xn = x2[n];
    float v0 = b1[lane] + a0 * W1rel[lane] + a1 * W1rel[128 + lane]
             + xn.x * W1rt[lane] + xn.y * W1rt[128 + lane];
    float v1 = b1[64 + lane] + a0 * W1rel[64 + lane] + a1 * W1rel[192 + lane]
             + xn.x * W1rt[64 + lane] + xn.y * W1rt[192 + lane];
    h1[(size_t)n * 128 + lane]      = fmaxf(v0, 0.f);
    h1[(size_t)n * 128 + 64 + lane] = fmaxf(v1, 0.f);
}

// ---------------- gather aggregation, bf16 p-table ----------------
// one wave per node; lane owns a bf162 feature-pair (fp = lane&31);
// half-waves split the edge list by parity; one shfl_xor(32) combines.

__global__ __launch_bounds__(256) void gather_b16_kernel(
    const float2* __restrict__ csr, const int* __restrict__ off,
    const int* __restrict__ deg, const __hip_bfloat162* __restrict__ p,
    float* __restrict__ agg, int N)
{
    int t = blockIdx.x * blockDim.x + threadIdx.x;
    int n = t >> 6;
    if (n >= N) return;
    int lane = t & 63;
    int half = lane >> 5;
    int fp = lane & 31;
    int beg = off[n], cnt = deg[n];
    float a0 = 0.f, a1 = 0.f;
    int i = half;
    for (; i + 2 < cnt; i += 4) {
        float2 c0 = csr[beg + i];
        float2 c1 = csr[beg + i + 2];
        float2 v0 = __bfloat1622float2(p[(size_t)__float_as_int(c0.x) * 32 + fp]);
        float2 v1 = __bfloat1622float2(p[(size_t)__float_as_int(c1.x) * 32 + fp]);
        a0 = fmaf(c0.y, v0.x, a0); a1 = fmaf(c0.y, v0.y, a1);
        a0 = fmaf(c1.y, v1.x, a0); a1 = fmaf(c1.y, v1.y, a1);
    }
    for (; i < cnt; i += 2) {
        float2 c = csr[beg + i];
        float2 v = __bfloat1622float2(p[(size_t)__float_as_int(c.x) * 32 + fp]);
        a0 = fmaf(c.y, v.x, a0); a1 = fmaf(c.y, v.y, a1);
    }
    a0 += __shfl_xor(a0, 32, 64);
    a1 += __shfl_xor(a1, 32, 64);
    if (half == 0)
        ((float2*)agg)[(size_t)n * 32 + fp] = make_float2(a0, a1);
}

// ---------------- fallback atomic path (if ws too small) ----------------

__global__ __launch_bounds__(256) void scatter_f64_kernel(
    const int* __restrict__ src, const int* __restrict__ dst,
    const float* __restrict__ ew, const float* __restrict__ p,
    float* __restrict__ agg, int E)
{
    int t = blockIdx.x * blockDim.x + threadIdx.x;
    int e = t >> 6;
    if (e >= E) return;
    int j = t & 63;
    atomicAdd(&agg[(size_t)dst[e] * 64 + j], p[(size_t)src[e] * 64 + j] * ew[e]);
}

__global__ __launch_bounds__(256) void scatter_f2_kernel(
    const int* __restrict__ src, const int* __restrict__ dst,
    const float* __restrict__ ew, const float* __restrict__ x,
    float* __restrict__ agg, int E)
{
    int e = blockIdx.x * blockDim.x + threadIdx.x;
    if (e >= E) return;
    int s = src[e], d = dst[e];
    float w = ew[e];
    atomicAdd(&agg[d * 2 + 0], x[s * 2 + 0] * w);
    atomicAdd(&agg[d * 2 + 1], x[s * 2 + 1] * w);
}

__global__ __launch_bounds__(256) void layer1_kernel(
    const float* __restrict__ x, const float* __restrict__ agg,
    const float* __restrict__ W1rel, const float* __restrict__ W1root,
    const float* __restrict__ b1, float* __restrict__ h1, int N)
{
    int t = blockIdx.x * blockDim.x + threadIdx.x;
    if (t >= N * 128) return;
    int n = t >> 7, j = t & 127;
    float v = b1[j]
        + agg[n * 2 + 0] * W1rel[j] + agg[n * 2 + 1] * W1rel[128 + j]
        + x[n * 2 + 0] * W1root[j] + x[n * 2 + 1] * W1root[128 + j];
    h1[t] = fmaxf(v, 0.f);
}

// ---------------- small-K dense GEMM: out = act(in@W + bias + extra) ------

template <int K, int NOUT, bool RELU, bool HAS_EXTRA, bool HAS_BIAS, bool OUT_BF16>
__global__ __launch_bounds__(256) void gemm_small(
    const float* __restrict__ in, int M,
    const float* __restrict__ W, int ldw, int woff,
    const float* __restrict__ bias,
    const float* __restrict__ extra,
    void* __restrict__ out_)
{
    constexpr int CPT = NOUT / 64;
    __shared__ float sW[K * NOUT];
    __shared__ float sX[4][K];
    const int tid = threadIdx.x;
    const int lane = tid & 63;
    const int wv = tid >> 6;

    for (int idx = tid; idx < K * NOUT; idx += 256) {
        int k = idx / NOUT;
        int j = idx - k * NOUT;
        sW[idx] = W[(size_t)(k + woff) * ldw + j];
    }
    __syncthreads();

    const int ROWS = 32;
    int r0 = blockIdx.x * ROWS;
    for (int rr = wv; rr < ROWS; rr += 4) {
        int r = r0 + rr;
        if (r >= M) break;
        #pragma unroll
        for (int kk = lane; kk < K; kk += 64) sX[wv][kk] = in[(size_t)r * K + kk];

        float acc[CPT][4];
        #pragma unroll
        for (int c = 0; c < CPT; c++)
            #pragma unroll
            for (int u = 0; u < 4; u++) acc[c][u] = 0.f;

        #pragma unroll
        for (int k = 0; k < K; k += 4) {
            #pragma unroll
            for (int u = 0; u < 4; u++) {
                float xv = sX[wv][k + u];
                #pragma unroll
                for (int c = 0; c < CPT; c++)
                    acc[c][u] = fmaf(xv, sW[(k + u) * NOUT + c * 64 + lane], acc[c][u]);
            }
        }
        #pragma unroll
        for (int c = 0; c < CPT; c++) {
            float v = (acc[c][0] + acc[c][1]) + (acc[c][2] + acc[c][3]);
            int j = c * 64 + lane;
            if (HAS_EXTRA) v += extra[(size_t)r * NOUT + j];
            if (HAS_BIAS) v += bias[j];
            if (RELU) v = fmaxf(v, 0.f);
            if (OUT_BF16)
                ((__hip_bfloat16*)out_)[(size_t)r * NOUT + j] = __float2bfloat16(v);
            else
                ((float*)out_)[(size_t)r * NOUT + j] = v;
        }
    }
}

// ---------------- decoder: 16-lane segment per edge, persistent ----------

__global__ __launch_bounds__(256) void decoder16_kernel(
    const int* __restrict__ src, const int* __restrict__ dst,
    const uint4* __restrict__ Za, const uint4* __restrict__ Zb,
    const float* __restrict__ db1, const float* __restrict__ dW2,
    const float* __restrict__ db2, float* __restrict__ pred,
    int Eobs, int nseg)
{
    int t = blockIdx.x * blockDim.x + threadIdx.x;
    int l = t & 15;              // lane within segment; owns elems 8l..8l+7
    int seg = t >> 4;
    float4 c1a = ((const float4*)db1)[2 * l];
    float4 c1b = ((const float4*)db1)[2 * l + 1];
    float4 w2a = ((const float4*)dW2)[2 * l];
    float4 w2b = ((const float4*)dW2)[2 * l + 1];
    float b2v = db2[0];

    for (int e = seg; e < Eobs; e += nseg) {
        int s = src[e], d = dst[e];
        uint4 ua = Za[(size_t)s * 16 + l];
        uint4 ub = Zb[(size_t)d * 16 + l];
        float acc;
        acc  = fmaxf(bf_lo(ua.x) + bf_lo(ub.x) + c1a.x, 0.f) * w2a.x;
        acc += fmaxf(bf_hi(ua.x) + bf_hi(ub.x) + c1a.y, 0.f) * w2a.y;
        acc += fmaxf(bf_lo(ua.y) + bf_lo(ub.y) + c1a.z, 0.f) * w2a.z;
        acc += fmaxf(bf_hi(ua.y) + bf_hi(ub.y) + c1a.w, 0.f) * w2a.w;
        acc += fmaxf(bf_lo(ua.z) + bf_lo(ub.z) + c1b.x, 0.f) * w2b.x;
        acc += fmaxf(bf_hi(ua.z) + bf_hi(ub.z) + c1b.y, 0.f) * w2b.y;
        acc += fmaxf(bf_lo(ua.w) + bf_lo(ub.w) + c1b.z, 0.f) * w2b.z;
        acc += fmaxf(bf_hi(ua.w) + bf_hi(ub.w) + c1b.w, 0.f) * w2b.w;
        #pragma unroll
        for (int o = 8; o > 0; o >>= 1) acc += __shfl_xor(acc, o, 64);
        if (l == 0) {
            float pv = acc + b2v;
            pred[e] = pv;
            pred[e + Eobs] = pv;
        }
    }
}

__global__ __launch_bounds__(256) void decoder_kernel(
    const int* __restrict__ src, const int* __restrict__ dst,
    const float* __restrict__ Z1a, const float* __restrict__ Z1b,
    const float* __restrict__ db1, const float* __restrict__ dW2,
    const float* __restrict__ db2, float* __restrict__ pred, int Eobs)
{
    int t = blockIdx.x * blockDim.x + threadIdx.x;
    int e = t >> 6;
    if (e >= Eobs) return;
    int lane = threadIdx.x & 63;
    int s = src[e], d = dst[e];
    float t0 = Z1a[(size_t)s * 128 + lane] + Z1b[(size_t)d * 128 + lane] + db1[lane];
    float t1 = Z1a[(size_t)s * 128 + lane + 64] + Z1b[(size_t)d * 128 + lane + 64] + db1[lane + 64];
    t0 = fmaxf(t0, 0.f);
    t1 = fmaxf(t1, 0.f);
    float acc = t0 * dW2[lane] + t1 * dW2[lane + 64];
    #pragma unroll
    for (int off = 32; off > 0; off >>= 1) acc += __shfl_xor(acc, off, 64);
    if (lane == 0) {
        float pv = acc + db2[0];
        pred[e] = pv;
        pred[e + Eobs] = pv;
    }
}

// ---------------- launch ----------------

extern "C" void kernel_launch(void* const* d_in, const int* in_sizes, int n_in,
                              void* d_out, int out_size, void* d_ws, size_t ws_size,
                              hipStream_t stream)
{
    const float* x     = (const float*)d_in[0];
    const int*   ei    = (const int*)d_in[1];
    const float* ew    = (const float*)d_in[2];
    const float* W1rel = (const float*)d_in[4];
    const float* b1    = (const float*)d_in[5];
    const float* W1rt  = (const float*)d_in[6];
    const float* W2rel = (const float*)d_in[7];
    const float* b2    = (const float*)d_in[8];
    const float* W2rt  = (const float*)d_in[9];
    const float* W3rel = (const float*)d_in[10];
    const float* b3    = (const float*)d_in[11];
    const float* W3rt  = (const float*)d_in[12];
    const float* dW1   = (const float*)d_in[13];
    const float* db1   = (const float*)d_in[14];
    const float* dW2   = (const float*)d_in[15];
    const float* db2   = (const float*)d_in[16];

    const int E    = in_sizes[2];
    const int N    = in_sizes[0] / 2;
    const int Eobs = E / 2;
    const int* src = ei;
    const int* dst = ei + E;

    // ws layout (floats):
    // [agg N*64][h1 N*128][h2 N*64][pbuf N*64][deg N][curs N][off N][p1 1024][p2 1024][csr E*2]
    float* agg  = (float*)d_ws;
    float* h1   = agg + (size_t)N * 64;
    float* h2   = h1 + (size_t)N * 128;
    float* pbuf = h2 + (size_t)N * 64;
    int*   deg  = (int*)(pbuf + (size_t)N * 64);
    int*   curs = deg + N;
    int*   off  = curs + N;
    int*   par1 = off + N;
    int*   par2 = par1 + 1024;
    float2* csr = (float2*)(par2 + 1024);

    size_t need = ((size_t)N * 320 + (size_t)N * 3 + 2048) * 4 + (size_t)E * 8;
    const bool use_csr = (ws_size >= need);

    float* pred = (float*)d_out;
    float* z    = pred + E;
    __hip_bfloat16* Z1a16 = (__hip_bfloat16*)h1;   // h1 dead after layer-2
    __hip_bfloat16* Z1b16 = (__hip_bfloat16*)h2;   // h2 dead after layer-3
    __hip_bfloat16* pb16  = (__hip_bfloat16*)pbuf;

    const int nscan = cdiv(N, 1024);

    if (use_csr) {
        // ---- CSR build (reused for all three aggregations) ----
        hipMemsetAsync(deg, 0, (size_t)N * 2 * sizeof(int), stream);  // deg + curs
        hist_kernel<<<cdiv(E, 256), 256, 0, stream>>>(dst, deg, E);
        scan_block_kernel<<<nscan, 1024, 0, stream>>>(deg, off, par1, N);
        scan_block_kernel<<<1, 1024, 0, stream>>>(par1, par2, nullptr, nscan);
        scan_add_kernel<<<cdiv(N, 1024), 1024, 0, stream>>>(off, par2, N);
        fill_csr_kernel<<<cdiv(E, 256), 256, 0, stream>>>(src, dst, ew, off, curs, csr, E);

        // ---- layer 1 (fused CSR gather + expansion) ----
        layer1_fused_kernel<<<cdiv((long long)N * 64, 256), 256, 0, stream>>>(
            (const float2*)x, csr, off, deg, W1rel, W1rt, b1, h1, N);

        // ---- layer 2 (rel-projection in bf16 for the gather) ----
        gemm_small<128, 64, false, false, false, true><<<cdiv(N, 32), 256, 0, stream>>>(
            h1, N, W2rel, 64, 0, nullptr, nullptr, pb16);
        gather_b16_kernel<<<cdiv((long long)N * 64, 256), 256, 0, stream>>>(
            csr, off, deg, (const __hip_bfloat162*)pb16, agg, N);
        gemm_small<128, 64, true, true, true, false><<<cdiv(N, 32), 256, 0, stream>>>(
            h1, N, W2rt, 64, 0, b2, agg, h2);

        // ---- layer 3 ----
        gemm_small<64, 64, false, false, false, true><<<cdiv(N, 32), 256, 0, stream>>>(
            h2, N, W3rel, 64, 0, nullptr, nullptr, pb16);
        gather_b16_kernel<<<cdiv((long long)N * 64, 256), 256, 0, stream>>>(
            csr, off, deg, (const __hip_bfloat162*)pb16, agg, N);
        gemm_small<64, 64, false, true, true, false><<<cdiv(N, 32), 256, 0, stream>>>(
            h2, N, W3rt, 64, 0, b3, agg, z);

        // ---- decoder (bf16 tables, 16-lane segments, persistent) ----
        gemm_small<64, 128, false, false, false, true><<<cdiv(N, 32), 256, 0, stream>>>(
            z, N, dW1, 128, 0, nullptr, nullptr, Z1a16);
        gemm_small<64, 128, false, false, false, true><<<cdiv(N, 32), 256, 0, stream>>>(
            z, N, dW1, 128, 64, nullptr, nullptr, Z1b16);
        int dblocks = 2048;
        if (dblocks > cdiv((long long)Eobs * 16, 256)) dblocks = cdiv((long long)Eobs * 16, 256);
        int nseg = dblocks * 16;
        decoder16_kernel<<<dblocks, 256, 0, stream>>>(
            src, dst, (const uint4*)Z1a16, (const uint4*)Z1b16,
            db1, dW2, db2, pred, Eobs, nseg);
    } else {
        // ---- fallback: atomic scatter path (fp32 throughout) ----
        float* Z1a = h1;
        float* Z1b = h2;
        hipMemsetAsync(agg, 0, (size_t)N * 2 * sizeof(float), stream);
        scatter_f2_kernel<<<cdiv(E, 256), 256, 0, stream>>>(src, dst, ew, x, agg, E);
        layer1_kernel<<<cdiv((long long)N * 128, 256), 256, 0, stream>>>(x, agg, W1rel, W1rt, b1, h1, N);

        gemm_small<128, 64, false, false, false, false><<<cdiv(N, 32), 256, 0, stream>>>(
            h1, N, W2rel, 64, 0, nullptr, nullptr, pbuf);
        hipMemsetAsync(agg, 0, (size_t)N * 64 * sizeof(float), stream);
        scatter_f64_kernel<<<cdiv((long long)E * 64, 256), 256, 0, stream>>>(src, dst, ew, pbuf, agg, E);
        gemm_small<128, 64, true, true, true, false><<<cdiv(N, 32), 256, 0, stream>>>(
            h1, N, W2rt, 64, 0, b2, agg, h2);

        gemm_small<64, 64, false, false, false, false><<<cdiv(N, 32), 256, 0, stream>>>(
            h2, N, W3rel, 64, 0, nullptr, nullptr, pbuf);
        hipMemsetAsync(agg, 0, (size_t)N * 64 * sizeof(float), stream);
        scatter_f64_kernel<<<cdiv((long long)E * 64, 256), 256, 0, stream>>>(src, dst, ew, pbuf, agg, E);
        gemm_small<64, 64, false, true, true, false><<<cdiv(N, 32), 256, 0, stream>>>(
            h2, N, W3rt, 64, 0, b3, agg, z);

        gemm_small<64, 128, false, false, false, false><<<cdiv(N, 32), 256, 0, stream>>>(
            z, N, dW1, 128, 0, nullptr, nullptr, Z1a);
        gemm_small<64, 128, false, false, false, false><<<cdiv(N, 32), 256, 0, stream>>>(
            z, N, dW1, 128, 64, nullptr, nullptr, Z1b);
        decoder_kernel<<<cdiv((long long)Eobs * 64, 256), 256, 0, stream>>>(
            src, dst, Z1a, Z1b, db1, dW2, db2, pred, Eobs);
    }
}

// Round 5
// 630.786 us; speedup vs baseline: 2.1600x; 1.0404x over previous
//
#include <hip/hip_runtime.h>
#include <hip/hip_bf16.h>

static inline int cdiv(long long a, long long b) { return (int)((a + b - 1) / b); }

__device__ inline float bf_lo(unsigned u) { return __uint_as_float(u << 16); }
__device__ inline float bf_hi(unsigned u) { return __uint_as_float(u & 0xffff0000u); }

#define CHUNK 8192

// ---------------- bucketed CSR build (3 phases) ----------------
// P1: per-chunk LDS histogram over coarse buckets (128 nodes each) + per-node deg
__global__ __launch_bounds__(256) void p1_hist_kernel(
    const int* __restrict__ dst, int* __restrict__ ghist,
    int* __restrict__ deg, int E, int nchunks, int nb)
{
    __shared__ int sh[512];
    int c = blockIdx.x;
    for (int i = threadIdx.x; i < nb; i += 256) sh[i] = 0;
    __syncthreads();
    int base = c * CHUNK;
    int end = min(base + CHUNK, E);
    for (int i = base + threadIdx.x; i < end; i += 256) {
        int d = dst[i];
        atomicAdd(&sh[d >> 7], 1);
        atomicAdd(&deg[d], 1);
    }
    __syncthreads();
    for (int i = threadIdx.x; i < nb; i += 256)
        ghist[i * nchunks + c] = sh[i];
}

// P2: scatter edges into (bucket,chunk)-exclusive ranges (packed dst|src + w)
__global__ __launch_bounds__(256) void p2_scatter_kernel(
    const int* __restrict__ src, const int* __restrict__ dst,
    const float* __restrict__ ew, const int* __restrict__ gs,
    uint2* __restrict__ bpos, int E, int nchunks, int nb)
{
    __shared__ int cur[512];
    int c = blockIdx.x;
    for (int i = threadIdx.x; i < nb; i += 256) cur[i] = gs[i * nchunks + c];
    __syncthreads();
    int base = c * CHUNK;
    int end = min(base + CHUNK, E);
    for (int i = base + threadIdx.x; i < end; i += 256) {
        int d = dst[i];
        int pos = atomicAdd(&cur[d >> 7], 1);
        bpos[pos] = make_uint2(((unsigned)d << 16) | (unsigned)src[i],
                               __float_as_uint(ew[i]));
    }
}

// P3: one block per bucket; LDS per-node cursors place edges into final CSR
__global__ __launch_bounds__(256) void p3_place_kernel(
    const uint2* __restrict__ bpos, const int* __restrict__ gs,
    const int* __restrict__ off, float2* __restrict__ csr,
    int E, int nchunks, int nb)
{
    __shared__ int cur[128];
    int b = blockIdx.x;
    int nodebase = b << 7;
    if (threadIdx.x < 128) cur[threadIdx.x] = 0;
    __syncthreads();
    int begin = gs[b * nchunks];
    int bend = (b + 1 < nb) ? gs[(b + 1) * nchunks] : E;
    for (int i = begin + threadIdx.x; i < bend; i += 256) {
        uint2 en = bpos[i];
        int d = en.x >> 16;
        int s = en.x & 0xffff;
        int pos = off[d] + atomicAdd(&cur[d - nodebase], 1);
        csr[pos] = make_float2(__int_as_float(s), __uint_as_float(en.y));
    }
}

// ---------------- scan helpers ----------------

__global__ __launch_bounds__(1024) void scan_block_kernel(
    const int* __restrict__ in, int* __restrict__ out,
    int* __restrict__ partials, int N)
{
    __shared__ int sdata[1024];
    const int tid = threadIdx.x;
    const int i = blockIdx.x * 1024 + tid;
    int v = (i < N) ? in[i] : 0;
    sdata[tid] = v;
    __syncthreads();
    #pragma unroll
    for (int ofs = 1; ofs < 1024; ofs <<= 1) {
        int t = (tid >= ofs) ? sdata[tid - ofs] : 0;
        __syncthreads();
        sdata[tid] += t;
        __syncthreads();
    }
    if (i < N) out[i] = sdata[tid] - v;
    if (partials && tid == 1023) partials[blockIdx.x] = sdata[1023];
}

__global__ __launch_bounds__(1024) void scan_add_kernel(
    int* __restrict__ off, const int* __restrict__ blockoff, int N)
{
    int i = blockIdx.x * blockDim.x + threadIdx.x;
    if (i < N) off[i] += blockoff[i >> 10];
}

// ---------------- fallback CSR build ----------------

__global__ __launch_bounds__(256) void hist_kernel(
    const int* __restrict__ dst, int* __restrict__ deg, int E)
{
    int e = blockIdx.x * blockDim.x + threadIdx.x;
    if (e < E) atomicAdd(&deg[dst[e]], 1);
}

__global__ __launch_bounds__(256) void fill_csr_kernel(
    const int* __restrict__ src, const int* __restrict__ dst,
    const float* __restrict__ ew, const int* __restrict__ off,
    int* __restrict__ cursor, float2* __restrict__ csr, int E)
{
    int e = blockIdx.x * blockDim.x + threadIdx.x;
    if (e >= E) return;
    int d = dst[e];
    int i = off[d] + atomicAdd(&cursor[d], 1);
    csr[i] = make_float2(__int_as_float(src[e]), ew[e]);
}

// ---------------- fused layer 1: CSR gather (2 feats) + expand to 128 -----

__global__ __launch_bounds__(256) void layer1_fused_kernel(
    const float2* __restrict__ x2, const float2* __restrict__ csr,
    const int* __restrict__ off, const int* __restrict__ deg,
    const float* __restrict__ W1rel, const float* __restrict__ W1rt,
    const float* __restrict__ b1, float* __restrict__ h1, int N)
{
    int t = blockIdx.x * blockDim.x + threadIdx.x;
    int n = t >> 6;
    if (n >= N) return;
    int lane = t & 63;
    int beg = off[n], cnt = deg[n];
    float a0 = 0.f, a1 = 0.f;
    for (int i = lane; i < cnt; i += 64) {
        float2 c = csr[beg + i];
        float2 xs = x2[__float_as_int(c.x)];
        a0 = fmaf(c.y, xs.x, a0);
        a1 = fmaf(c.y, xs.y, a1);
    }
    #pragma unroll
    for (int o = 32; o > 0; o >>= 1) {
        a0 += __shfl_xor(a0, o, 64);
        a1 += __shfl_xor(a1, o, 64);
    }
    float2 xn = x2[n];
    float v0 = b1[lane] + a0 * W1rel[lane] + a1 * W1rel[128 + lane]
             + xn.x * W1rt[lane] + xn.y * W1rt[128 + lane];
    float v1 = b1[64 + lane] + a0 * W1rel[64 + lane] + a1 * W1rel[192 + lane]
             + xn.x * W1rt[64 + lane] + xn.y * W1rt[192 + lane];
    h1[(size_t)n * 128 + lane]      = fmaxf(v0, 0.f);
    h1[(size_t)n * 128 + 64 + lane] = fmaxf(v1, 0.f);
}

// ---------------- gather aggregation, bf16 p-table ----------------

__global__ __launch_bounds__(256) void gather_b16_kernel(
    const float2* __restrict__ csr, const int* __restrict__ off,
    const int* __restrict__ deg, const __hip_bfloat162* __restrict__ p,
    float* __restrict__ agg, int N)
{
    int t = blockIdx.x * blockDim.x + threadIdx.x;
    int n = t >> 6;
    if (n >= N) return;
    int lane = t & 63;
    int half = lane >> 5;
    int fp = lane & 31;
    int beg = off[n], cnt = deg[n];
    float a0 = 0.f, a1 = 0.f;
    int i = half;
    for (; i + 2 < cnt; i += 4) {
        float2 c0 = csr[beg + i];
        float2 c1 = csr[beg + i + 2];
        float2 v0 = __bfloat1622float2(p[(size_t)__float_as_int(c0.x) * 32 + fp]);
        float2 v1 = __bfloat1622float2(p[(size_t)__float_as_int(c1.x) * 32 + fp]);
        a0 = fmaf(c0.y, v0.x, a0); a1 = fmaf(c0.y, v0.y, a1);
        a0 = fmaf(c1.y, v1.x, a0); a1 = fmaf(c1.y, v1.y, a1);
    }
    for (; i < cnt; i += 2) {
        float2 c = csr[beg + i];
        float2 v = __bfloat1622float2(p[(size_t)__float_as_int(c.x) * 32 + fp]);
        a0 = fmaf(c.y, v.x, a0); a1 = fmaf(c.y, v.y, a1);
    }
    a0 += __shfl_xor(a0, 32, 64);
    a1 += __shfl_xor(a1, 32, 64);
    if (half == 0)
        ((float2*)agg)[(size_t)n * 32 + fp] = make_float2(a0, a1);
}

// ---------------- fallback atomic path (if ws too small) ----------------

__global__ __launch_bounds__(256) void scatter_f64_kernel(
    const int* __restrict__ src, const int* __restrict__ dst,
    const float* __restrict__ ew, const float* __restrict__ p,
    float* __restrict__ agg, int E)
{
    int t = blockIdx.x * blockDim.x + threadIdx.x;
    int e = t >> 6;
    if (e >= E) return;
    int j = t & 63;
    atomicAdd(&agg[(size_t)dst[e] * 64 + j], p[(size_t)src[e] * 64 + j] * ew[e]);
}

__global__ __launch_bounds__(256) void scatter_f2_kernel(
    const int* __restrict__ src, const int* __restrict__ dst,
    const float* __restrict__ ew, const float* __restrict__ x,
    float* __restrict__ agg, int E)
{
    int e = blockIdx.x * blockDim.x + threadIdx.x;
    if (e >= E) return;
    int s = src[e], d = dst[e];
    float w = ew[e];
    atomicAdd(&agg[d * 2 + 0], x[s * 2 + 0] * w);
    atomicAdd(&agg[d * 2 + 1], x[s * 2 + 1] * w);
}

__global__ __launch_bounds__(256) void layer1_kernel(
    const float* __restrict__ x, const float* __restrict__ agg,
    const float* __restrict__ W1rel, const float* __restrict__ W1root,
    const float* __restrict__ b1, float* __restrict__ h1, int N)
{
    int t = blockIdx.x * blockDim.x + threadIdx.x;
    if (t >= N * 128) return;
    int n = t >> 7, j = t & 127;
    float v = b1[j]
        + agg[n * 2 + 0] * W1rel[j] + agg[n * 2 + 1] * W1rel[128 + j]
        + x[n * 2 + 0] * W1root[j] + x[n * 2 + 1] * W1root[128 + j];
    h1[t] = fmaxf(v, 0.f);
}

// ---------------- small-K dense GEMM: out = act(in@W + bias + extra) ------

template <int K, int NOUT, bool RELU, bool HAS_EXTRA, bool HAS_BIAS, bool OUT_BF16>
__global__ __launch_bounds__(256) void gemm_small(
    const float* __restrict__ in, int M,
    const float* __restrict__ W, int ldw, int woff,
    const float* __restrict__ bias,
    const float* __restrict__ extra,
    void* __restrict__ out_)
{
    constexpr int CPT = NOUT / 64;
    __shared__ float sW[K * NOUT];
    __shared__ float sX[4][K];
    const int tid = threadIdx.x;
    const int lane = tid & 63;
    const int wv = tid >> 6;

    for (int idx = tid; idx < K * NOUT; idx += 256) {
        int k = idx / NOUT;
        int j = idx - k * NOUT;
        sW[idx] = W[(size_t)(k + woff) * ldw + j];
    }
    __syncthreads();

    const int ROWS = 32;
    int r0 = blockIdx.x * ROWS;
    for (int rr = wv; rr < ROWS; rr += 4) {
        int r = r0 + rr;
        if (r >= M) break;
        #pragma unroll
        for (int kk = lane; kk < K; kk += 64) sX[wv][kk] = in[(size_t)r * K + kk];

        float acc[CPT][4];
        #pragma unroll
        for (int c = 0; c < CPT; c++)
            #pragma unroll
            for (int u = 0; u < 4; u++) acc[c][u] = 0.f;

        #pragma unroll
        for (int k = 0; k < K; k += 4) {
            #pragma unroll
            for (int u = 0; u < 4; u++) {
                float xv = sX[wv][k + u];
                #pragma unroll
                for (int c = 0; c < CPT; c++)
                    acc[c][u] = fmaf(xv, sW[(k + u) * NOUT + c * 64 + lane], acc[c][u]);
            }
        }
        #pragma unroll
        for (int c = 0; c < CPT; c++) {
            float v = (acc[c][0] + acc[c][1]) + (acc[c][2] + acc[c][3]);
            int j = c * 64 + lane;
            if (HAS_EXTRA) v += extra[(size_t)r * NOUT + j];
            if (HAS_BIAS) v += bias[j];
            if (RELU) v = fmaxf(v, 0.f);
            if (OUT_BF16)
                ((__hip_bfloat16*)out_)[(size_t)r * NOUT + j] = __float2bfloat16(v);
            else
                ((float*)out_)[(size_t)r * NOUT + j] = v;
        }
    }
}

// ---------------- decoder: 16-lane segment per edge, persistent ----------

__global__ __launch_bounds__(256) void decoder16_kernel(
    const int* __restrict__ src, const int* __restrict__ dst,
    const uint4* __restrict__ Za, const uint4* __restrict__ Zb,
    const float* __restrict__ db1, const float* __restrict__ dW2,
    const float* __restrict__ db2, float* __restrict__ pred,
    int Eobs, int nseg)
{
    int t = blockIdx.x * blockDim.x + threadIdx.x;
    int l = t & 15;
    int seg = t >> 4;
    float4 c1a = ((const float4*)db1)[2 * l];
    float4 c1b = ((const float4*)db1)[2 * l + 1];
    float4 w2a = ((const float4*)dW2)[2 * l];
    float4 w2b = ((const float4*)dW2)[2 * l + 1];
    float b2v = db2[0];

    for (int e = seg; e < Eobs; e += nseg) {
        int s = src[e], d = dst[e];
        uint4 ua = Za[(size_t)s * 16 + l];
        uint4 ub = Zb[(size_t)d * 16 + l];
        float acc;
        acc  = fmaxf(bf_lo(ua.x) + bf_lo(ub.x) + c1a.x, 0.f) * w2a.x;
        acc += fmaxf(bf_hi(ua.x) + bf_hi(ub.x) + c1a.y, 0.f) * w2a.y;
        acc += fmaxf(bf_lo(ua.y) + bf_lo(ub.y) + c1a.z, 0.f) * w2a.z;
        acc += fmaxf(bf_hi(ua.y) + bf_hi(ub.y) + c1a.w, 0.f) * w2a.w;
        acc += fmaxf(bf_lo(ua.z) + bf_lo(ub.z) + c1b.x, 0.f) * w2b.x;
        acc += fmaxf(bf_hi(ua.z) + bf_hi(ub.z) + c1b.y, 0.f) * w2b.y;
        acc += fmaxf(bf_lo(ua.w) + bf_lo(ub.w) + c1b.z, 0.f) * w2b.z;
        acc += fmaxf(bf_hi(ua.w) + bf_hi(ub.w) + c1b.w, 0.f) * w2b.w;
        #pragma unroll
        for (int o = 8; o > 0; o >>= 1) acc += __shfl_xor(acc, o, 64);
        if (l == 0) {
            float pv = acc + b2v;
            pred[e] = pv;
            pred[e + Eobs] = pv;
        }
    }
}

__global__ __launch_bounds__(256) void decoder_kernel(
    const int* __restrict__ src, const int* __restrict__ dst,
    const float* __restrict__ Z1a, const float* __restrict__ Z1b,
    const float* __restrict__ db1, const float* __restrict__ dW2,
    const float* __restrict__ db2, float* __restrict__ pred, int Eobs)
{
    int t = blockIdx.x * blockDim.x + threadIdx.x;
    int e = t >> 6;
    if (e >= Eobs) return;
    int lane = threadIdx.x & 63;
    int s = src[e], d = dst[e];
    float t0 = Z1a[(size_t)s * 128 + lane] + Z1b[(size_t)d * 128 + lane] + db1[lane];
    float t1 = Z1a[(size_t)s * 128 + lane + 64] + Z1b[(size_t)d * 128 + lane + 64] + db1[lane + 64];
    t0 = fmaxf(t0, 0.f);
    t1 = fmaxf(t1, 0.f);
    float acc = t0 * dW2[lane] + t1 * dW2[lane + 64];
    #pragma unroll
    for (int off = 32; off > 0; off >>= 1) acc += __shfl_xor(acc, off, 64);
    if (lane == 0) {
        float pv = acc + db2[0];
        pred[e] = pv;
        pred[e + Eobs] = pv;
    }
}

// ---------------- launch ----------------

extern "C" void kernel_launch(void* const* d_in, const int* in_sizes, int n_in,
                              void* d_out, int out_size, void* d_ws, size_t ws_size,
                              hipStream_t stream)
{
    const float* x     = (const float*)d_in[0];
    const int*   ei    = (const int*)d_in[1];
    const float* ew    = (const float*)d_in[2];
    const float* W1rel = (const float*)d_in[4];
    const float* b1    = (const float*)d_in[5];
    const float* W1rt  = (const float*)d_in[6];
    const float* W2rel = (const float*)d_in[7];
    const float* b2    = (const float*)d_in[8];
    const float* W2rt  = (const float*)d_in[9];
    const float* W3rel = (const float*)d_in[10];
    const float* b3    = (const float*)d_in[11];
    const float* W3rt  = (const float*)d_in[12];
    const float* dW1   = (const float*)d_in[13];
    const float* db1   = (const float*)d_in[14];
    const float* dW2   = (const float*)d_in[15];
    const float* db2   = (const float*)d_in[16];

    const int E    = in_sizes[2];
    const int N    = in_sizes[0] / 2;
    const int Eobs = E / 2;
    const int* src = ei;
    const int* dst = ei + E;

    // ws layout (floats):
    // [agg N*64][h1 N*128][h2 N*64][pbuf N*64][deg N][curs N][off N][p1 1024][p2 1024][csr E*2]
    float* agg  = (float*)d_ws;
    float* h1   = agg + (size_t)N * 64;
    float* h2   = h1 + (size_t)N * 128;
    float* pbuf = h2 + (size_t)N * 64;
    int*   deg  = (int*)(pbuf + (size_t)N * 64);
    int*   curs = deg + N;
    int*   off  = curs + N;
    int*   par1 = off + N;
    int*   par2 = par1 + 1024;
    float2* csr = (float2*)(par2 + 1024);

    size_t need = ((size_t)N * 320 + (size_t)N * 3 + 2048) * 4 + (size_t)E * 8;
    const bool use_csr = (ws_size >= need);

    // fast-build aliases (h1/h2 are dead during CSR build)
    uint2* bpos   = (uint2*)h1;     // E * 8 B <= N*128*4 B
    int*   ghist  = (int*)h2;
    const int nb      = (N + 127) >> 7;
    const int nchunks = cdiv(E, CHUNK);
    const int M       = nb * nchunks;
    int*   ghist_s = ghist + M;
    const bool fast_build = use_csr && nb <= 512 && N <= 65535 &&
                            (size_t)E * 2 <= (size_t)N * 128 &&
                            (size_t)M * 2 <= (size_t)N * 64;

    float* pred = (float*)d_out;
    float* z    = pred + E;
    __hip_bfloat16* Z1a16 = (__hip_bfloat16*)h1;   // h1 dead after layer-2
    __hip_bfloat16* Z1b16 = (__hip_bfloat16*)h2;   // h2 dead after layer-3
    __hip_bfloat16* pb16  = (__hip_bfloat16*)pbuf;

    const int nscan  = cdiv(N, 1024);
    const int nscanM = cdiv(M, 1024);

    if (use_csr) {
        // ---- CSR build ----
        if (fast_build) {
            hipMemsetAsync(deg, 0, (size_t)N * sizeof(int), stream);
            p1_hist_kernel<<<nchunks, 256, 0, stream>>>(dst, ghist, deg, E, nchunks, nb);
            // off = exclusive scan of deg
            scan_block_kernel<<<nscan, 1024, 0, stream>>>(deg, off, par1, N);
            scan_block_kernel<<<1, 1024, 0, stream>>>(par1, par2, nullptr, nscan);
            scan_add_kernel<<<cdiv(N, 1024), 1024, 0, stream>>>(off, par2, N);
            // ghist_s = exclusive scan of ghist (bucket-major)
            scan_block_kernel<<<nscanM, 1024, 0, stream>>>(ghist, ghist_s, par1, M);
            scan_block_kernel<<<1, 1024, 0, stream>>>(par1, par2, nullptr, nscanM);
            scan_add_kernel<<<cdiv(M, 1024), 1024, 0, stream>>>(ghist_s, par2, M);
            p2_scatter_kernel<<<nchunks, 256, 0, stream>>>(src, dst, ew, ghist_s, bpos, E, nchunks, nb);
            p3_place_kernel<<<nb, 256, 0, stream>>>(bpos, ghist_s, off, csr, E, nchunks, nb);
        } else {
            hipMemsetAsync(deg, 0, (size_t)N * 2 * sizeof(int), stream);  // deg + curs
            hist_kernel<<<cdiv(E, 256), 256, 0, stream>>>(dst, deg, E);
            scan_block_kernel<<<nscan, 1024, 0, stream>>>(deg, off, par1, N);
            scan_block_kernel<<<1, 1024, 0, stream>>>(par1, par2, nullptr, nscan);
            scan_add_kernel<<<cdiv(N, 1024), 1024, 0, stream>>>(off, par2, N);
            fill_csr_kernel<<<cdiv(E, 256), 256, 0, stream>>>(src, dst, ew, off, curs, csr, E);
        }

        // ---- layer 1 (fused CSR gather + expansion) ----
        layer1_fused_kernel<<<cdiv((long long)N * 64, 256), 256, 0, stream>>>(
            (const float2*)x, csr, off, deg, W1rel, W1rt, b1, h1, N);

        // ---- layer 2 (rel-projection in bf16 for the gather) ----
        gemm_small<128, 64, false, false, false, true><<<cdiv(N, 32), 256, 0, stream>>>(
            h1, N, W2rel, 64, 0, nullptr, nullptr, pb16);
        gather_b16_kernel<<<cdiv((long long)N * 64, 256), 256, 0, stream>>>(
            csr, off, deg, (const __hip_bfloat162*)pb16, agg, N);
        gemm_small<128, 64, true, true, true, false><<<cdiv(N, 32), 256, 0, stream>>>(
            h1, N, W2rt, 64, 0, b2, agg, h2);

        // ---- layer 3 ----
        gemm_small<64, 64, false, false, false, true><<<cdiv(N, 32), 256, 0, stream>>>(
            h2, N, W3rel, 64, 0, nullptr, nullptr, pb16);
        gather_b16_kernel<<<cdiv((long long)N * 64, 256), 256, 0, stream>>>(
            csr, off, deg, (const __hip_bfloat162*)pb16, agg, N);
        gemm_small<64, 64, false, true, true, false><<<cdiv(N, 32), 256, 0, stream>>>(
            h2, N, W3rt, 64, 0, b3, agg, z);

        // ---- decoder (bf16 tables, 16-lane segments, persistent) ----
        gemm_small<64, 128, false, false, false, true><<<cdiv(N, 32), 256, 0, stream>>>(
            z, N, dW1, 128, 0, nullptr, nullptr, Z1a16);
        gemm_small<64, 128, false, false, false, true><<<cdiv(N, 32), 256, 0, stream>>>(
            z, N, dW1, 128, 64, nullptr, nullptr, Z1b16);
        int dblocks = 2048;
        if (dblocks > cdiv((long long)Eobs * 16, 256)) dblocks = cdiv((long long)Eobs * 16, 256);
        int nseg = dblocks * 16;
        decoder16_kernel<<<dblocks, 256, 0, stream>>>(
            src, dst, (const uint4*)Z1a16, (const uint4*)Z1b16,
            db1, dW2, db2, pred, Eobs, nseg);
    } else {
        // ---- fallback: atomic scatter path (fp32 throughout) ----
        float* Z1a = h1;
        float* Z1b = h2;
        hipMemsetAsync(agg, 0, (size_t)N * 2 * sizeof(float), stream);
        scatter_f2_kernel<<<cdiv(E, 256), 256, 0, stream>>>(src, dst, ew, x, agg, E);
        layer1_kernel<<<cdiv((long long)N * 128, 256), 256, 0, stream>>>(x, agg, W1rel, W1rt, b1, h1, N);

        gemm_small<128, 64, false, false, false, false><<<cdiv(N, 32), 256, 0, stream>>>(
            h1, N, W2rel, 64, 0, nullptr, nullptr, pbuf);
        hipMemsetAsync(agg, 0, (size_t)N * 64 * sizeof(float), stream);
        scatter_f64_kernel<<<cdiv((long long)E * 64, 256), 256, 0, stream>>>(src, dst, ew, pbuf, agg, E);
        gemm_small<128, 64, true, true, true, false><<<cdiv(N, 32), 256, 0, stream>>>(
            h1, N, W2rt, 64, 0, b2, agg, h2);

        gemm_small<64, 64, false, false, false, false><<<cdiv(N, 32), 256, 0, stream>>>(
            h2, N, W3rel, 64, 0, nullptr, nullptr, pbuf);
        hipMemsetAsync(agg, 0, (size_t)N * 64 * sizeof(float), stream);
        scatter_f64_kernel<<<cdiv((long long)E * 64, 256), 256, 0, stream>>>(src, dst, ew, pbuf, agg, E);
        gemm_small<64, 64, false, true, true, false><<<cdiv(N, 32), 256, 0, stream>>>(
            h2, N, W3rt, 64, 0, b3, agg, z);

        gemm_small<64, 128, false, false, false, false><<<cdiv(N, 32), 256, 0, stream>>>(
            z, N, dW1, 128, 0, nullptr, nullptr, Z1a);
        gemm_small<64, 128, false, false, false, false><<<cdiv(N, 32), 256, 0, stream>>>(
            z, N, dW1, 128, 64, nullptr, nullptr, Z1b);
        decoder_kernel<<<cdiv((long long)Eobs * 64, 256), 256, 0, stream>>>(
            src, dst, Z1a, Z1b, db1, dW2, db2, pred, Eobs);
    }
}

// Round 6
// 545.682 us; speedup vs baseline: 2.4968x; 1.1560x over previous
//
#include <hip/hip_runtime.h>
#include <hip/hip_bf16.h>

static inline int cdiv(long long a, long long b) { return (int)((a + b - 1) / b); }

__device__ inline float bf_lo(unsigned u) { return __uint_as_float(u << 16); }
__device__ inline float bf_hi(unsigned u) { return __uint_as_float(u & 0xffff0000u); }

#define CHUNK 8192

// ---------------- bucketed CSR build (3 phases) ----------------
// P1: per-chunk LDS histogram over coarse buckets (128 nodes each). No global atomics.
__global__ __launch_bounds__(256) void p1_hist_kernel(
    const int* __restrict__ dst, int* __restrict__ ghist,
    int E, int nchunks, int nb)
{
    __shared__ int sh[512];
    int c = blockIdx.x;
    for (int i = threadIdx.x; i < nb; i += 256) sh[i] = 0;
    __syncthreads();
    int base = c * CHUNK;
    int end = min(base + CHUNK, E);
    for (int i = base + threadIdx.x; i < end; i += 256)
        atomicAdd(&sh[dst[i] >> 7], 1);
    __syncthreads();
    for (int i = threadIdx.x; i < nb; i += 256)
        ghist[i * nchunks + c] = sh[i];
}

// P2: scatter edges into (bucket,chunk)-exclusive ranges (packed dst|src + w)
__global__ __launch_bounds__(256) void p2_scatter_kernel(
    const int* __restrict__ src, const int* __restrict__ dst,
    const float* __restrict__ ew, const int* __restrict__ gs,
    uint2* __restrict__ bpos, int E, int nchunks, int nb)
{
    __shared__ int cur[512];
    int c = blockIdx.x;
    for (int i = threadIdx.x; i < nb; i += 256) cur[i] = gs[i * nchunks + c];
    __syncthreads();
    int base = c * CHUNK;
    int end = min(base + CHUNK, E);
    for (int i = base + threadIdx.x; i < end; i += 256) {
        int d = dst[i];
        int pos = atomicAdd(&cur[d >> 7], 1);
        bpos[pos] = make_uint2(((unsigned)d << 16) | (unsigned)src[i],
                               __float_as_uint(ew[i]));
    }
}

// P3: one block per bucket. Pass A: count per-node deg in LDS; LDS scan ->
// absolute CSR offsets; write deg/off coalesced. Pass B: place edges.
__global__ __launch_bounds__(256) void p3_place_kernel(
    const uint2* __restrict__ bpos, const int* __restrict__ gs,
    int* __restrict__ deg, int* __restrict__ off,
    float2* __restrict__ csr, int E, int nchunks, int nb, int N)
{
    __shared__ int cnt[128];
    __shared__ int pos[128];
    int b = blockIdx.x;
    int nodebase = b << 7;
    if (threadIdx.x < 128) cnt[threadIdx.x] = 0;
    __syncthreads();
    int begin = gs[b * nchunks];
    int bend = (b + 1 < nb) ? gs[(b + 1) * nchunks] : E;
    for (int i = begin + threadIdx.x; i < bend; i += 256)
        atomicAdd(&cnt[(bpos[i].x >> 16) - nodebase], 1);
    __syncthreads();
    int v = 0;
    if (threadIdx.x < 128) { v = cnt[threadIdx.x]; pos[threadIdx.x] = v; }
    __syncthreads();
    #pragma unroll
    for (int ofs = 1; ofs < 128; ofs <<= 1) {
        int t = 0;
        if (threadIdx.x < 128 && threadIdx.x >= ofs) t = pos[threadIdx.x - ofs];
        __syncthreads();
        if (threadIdx.x < 128) pos[threadIdx.x] += t;
        __syncthreads();
    }
    if (threadIdx.x < 128) {
        int ex = begin + pos[threadIdx.x] - v;   // absolute exclusive offset
        int n = nodebase + threadIdx.x;
        if (n < N) { off[n] = ex; deg[n] = v; }
        cnt[threadIdx.x] = ex;                   // reuse as cursor
    }
    __syncthreads();
    for (int i = begin + threadIdx.x; i < bend; i += 256) {
        uint2 en = bpos[i];
        int d = en.x >> 16;
        int p = atomicAdd(&cnt[d - nodebase], 1);
        csr[p] = make_float2(__int_as_float((int)(en.x & 0xffffu)),
                             __uint_as_float(en.y));
    }
}

// ---------------- scan helpers ----------------

__global__ __launch_bounds__(1024) void scan_block_kernel(
    const int* __restrict__ in, int* __restrict__ out,
    int* __restrict__ partials, int N)
{
    __shared__ int sdata[1024];
    const int tid = threadIdx.x;
    const int i = blockIdx.x * 1024 + tid;
    int v = (i < N) ? in[i] : 0;
    sdata[tid] = v;
    __syncthreads();
    #pragma unroll
    for (int ofs = 1; ofs < 1024; ofs <<= 1) {
        int t = (tid >= ofs) ? sdata[tid - ofs] : 0;
        __syncthreads();
        sdata[tid] += t;
        __syncthreads();
    }
    if (i < N) out[i] = sdata[tid] - v;
    if (partials && tid == 1023) partials[blockIdx.x] = sdata[1023];
}

__global__ __launch_bounds__(1024) void scan_add_kernel(
    int* __restrict__ off, const int* __restrict__ blockoff, int N)
{
    int i = blockIdx.x * blockDim.x + threadIdx.x;
    if (i < N) off[i] += blockoff[i >> 10];
}

// ---------------- fallback CSR build ----------------

__global__ __launch_bounds__(256) void hist_kernel(
    const int* __restrict__ dst, int* __restrict__ deg, int E)
{
    int e = blockIdx.x * blockDim.x + threadIdx.x;
    if (e < E) atomicAdd(&deg[dst[e]], 1);
}

__global__ __launch_bounds__(256) void fill_csr_kernel(
    const int* __restrict__ src, const int* __restrict__ dst,
    const float* __restrict__ ew, const int* __restrict__ off,
    int* __restrict__ cursor, float2* __restrict__ csr, int E)
{
    int e = blockIdx.x * blockDim.x + threadIdx.x;
    if (e >= E) return;
    int d = dst[e];
    int i = off[d] + atomicAdd(&cursor[d], 1);
    csr[i] = make_float2(__int_as_float(src[e]), ew[e]);
}

// ---------------- fused layer 1: CSR gather (2 feats) + expand to 128 -----

__global__ __launch_bounds__(256) void layer1_fused_kernel(
    const float2* __restrict__ x2, const float2* __restrict__ csr,
    const int* __restrict__ off, const int* __restrict__ deg,
    const float* __restrict__ W1rel, const float* __restrict__ W1rt,
    const float* __restrict__ b1, float* __restrict__ h1, int N)
{
    int t = blockIdx.x * blockDim.x + threadIdx.x;
    int n = t >> 6;
    if (n >= N) return;
    int lane = t & 63;
    int beg = off[n], cnt = deg[n];
    float a0 = 0.f, a1 = 0.f;
    for (int i = lane; i < cnt; i += 64) {
        float2 c = csr[beg + i];
        float2 xs = x2[__float_as_int(c.x)];
        a0 = fmaf(c.y, xs.x, a0);
        a1 = fmaf(c.y, xs.y, a1);
    }
    #pragma unroll
    for (int o = 32; o > 0; o >>= 1) {
        a0 += __shfl_xor(a0, o, 64);
        a1 += __shfl_xor(a1, o, 64);
    }
    float2 xn = x2[n];
    float v0 = b1[lane] + a0 * W1rel[lane] + a1 * W1rel[128 + lane]
             + xn.x * W1rt[lane] + xn.y * W1rt[128 + lane];
    float v1 = b1[64 + lane] + a0 * W1rel[64 + lane] + a1 * W1rel[192 + lane]
             + xn.x * W1rt[64 + lane] + xn.y * W1rt[192 + lane];
    h1[(size_t)n * 128 + lane]      = fmaxf(v0, 0.f);
    h1[(size_t)n * 128 + 64 + lane] = fmaxf(v1, 0.f);
}

// ---------------- gather aggregation, bf16 p-table ----------------

__global__ __launch_bounds__(256) void gather_b16_kernel(
    const float2* __restrict__ csr, const int* __restrict__ off,
    const int* __restrict__ deg, const __hip_bfloat162* __restrict__ p,
    float* __restrict__ agg, int N)
{
    int t = blockIdx.x * blockDim.x + threadIdx.x;
    int n = t >> 6;
    if (n >= N) return;
    int lane = t & 63;
    int half = lane >> 5;
    int fp = lane & 31;
    int beg = off[n], cnt = deg[n];
    float a0 = 0.f, a1 = 0.f;
    int i = half;
    for (; i + 2 < cnt; i += 4) {
        float2 c0 = csr[beg + i];
        float2 c1 = csr[beg + i + 2];
        float2 v0 = __bfloat1622float2(p[(size_t)__float_as_int(c0.x) * 32 + fp]);
        float2 v1 = __bfloat1622float2(p[(size_t)__float_as_int(c1.x) * 32 + fp]);
        a0 = fmaf(c0.y, v0.x, a0); a1 = fmaf(c0.y, v0.y, a1);
        a0 = fmaf(c1.y, v1.x, a0); a1 = fmaf(c1.y, v1.y, a1);
    }
    for (; i < cnt; i += 2) {
        float2 c = csr[beg + i];
        float2 v = __bfloat1622float2(p[(size_t)__float_as_int(c.x) * 32 + fp]);
        a0 = fmaf(c.y, v.x, a0); a1 = fmaf(c.y, v.y, a1);
    }
    a0 += __shfl_xor(a0, 32, 64);
    a1 += __shfl_xor(a1, 32, 64);
    if (half == 0)
        ((float2*)agg)[(size_t)n * 32 + fp] = make_float2(a0, a1);
}

// ---------------- fallback atomic path (if ws too small) ----------------

__global__ __launch_bounds__(256) void scatter_f64_kernel(
    const int* __restrict__ src, const int* __restrict__ dst,
    const float* __restrict__ ew, const float* __restrict__ p,
    float* __restrict__ agg, int E)
{
    int t = blockIdx.x * blockDim.x + threadIdx.x;
    int e = t >> 6;
    if (e >= E) return;
    int j = t & 63;
    atomicAdd(&agg[(size_t)dst[e] * 64 + j], p[(size_t)src[e] * 64 + j] * ew[e]);
}

__global__ __launch_bounds__(256) void scatter_f2_kernel(
    const int* __restrict__ src, const int* __restrict__ dst,
    const float* __restrict__ ew, const float* __restrict__ x,
    float* __restrict__ agg, int E)
{
    int e = blockIdx.x * blockDim.x + threadIdx.x;
    if (e >= E) return;
    int s = src[e], d = dst[e];
    float w = ew[e];
    atomicAdd(&agg[d * 2 + 0], x[s * 2 + 0] * w);
    atomicAdd(&agg[d * 2 + 1], x[s * 2 + 1] * w);
}

__global__ __launch_bounds__(256) void layer1_kernel(
    const float* __restrict__ x, const float* __restrict__ agg,
    const float* __restrict__ W1rel, const float* __restrict__ W1root,
    const float* __restrict__ b1, float* __restrict__ h1, int N)
{
    int t = blockIdx.x * blockDim.x + threadIdx.x;
    if (t >= N * 128) return;
    int n = t >> 7, j = t & 127;
    float v = b1[j]
        + agg[n * 2 + 0] * W1rel[j] + agg[n * 2 + 1] * W1rel[128 + j]
        + x[n * 2 + 0] * W1root[j] + x[n * 2 + 1] * W1root[128 + j];
    h1[t] = fmaxf(v, 0.f);
}

// ---------------- small-K dense GEMM: out = act(in@W + bias + extra) ------

template <int K, int NOUT, bool RELU, bool HAS_EXTRA, bool HAS_BIAS, bool OUT_BF16>
__global__ __launch_bounds__(256) void gemm_small(
    const float* __restrict__ in, int M,
    const float* __restrict__ W, int ldw, int woff,
    const float* __restrict__ bias,
    const float* __restrict__ extra,
    void* __restrict__ out_)
{
    constexpr int CPT = NOUT / 64;
    __shared__ float sW[K * NOUT];
    __shared__ float sX[4][K];
    const int tid = threadIdx.x;
    const int lane = tid & 63;
    const int wv = tid >> 6;

    for (int idx = tid; idx < K * NOUT; idx += 256) {
        int k = idx / NOUT;
        int j = idx - k * NOUT;
        sW[idx] = W[(size_t)(k + woff) * ldw + j];
    }
    __syncthreads();

    const int ROWS = 32;
    int r0 = blockIdx.x * ROWS;
    for (int rr = wv; rr < ROWS; rr += 4) {
        int r = r0 + rr;
        if (r >= M) break;
        #pragma unroll
        for (int kk = lane; kk < K; kk += 64) sX[wv][kk] = in[(size_t)r * K + kk];

        float acc[CPT][4];
        #pragma unroll
        for (int c = 0; c < CPT; c++)
            #pragma unroll
            for (int u = 0; u < 4; u++) acc[c][u] = 0.f;

        #pragma unroll
        for (int k = 0; k < K; k += 4) {
            #pragma unroll
            for (int u = 0; u < 4; u++) {
                float xv = sX[wv][k + u];
                #pragma unroll
                for (int c = 0; c < CPT; c++)
                    acc[c][u] = fmaf(xv, sW[(k + u) * NOUT + c * 64 + lane], acc[c][u]);
            }
        }
        #pragma unroll
        for (int c = 0; c < CPT; c++) {
            float v = (acc[c][0] + acc[c][1]) + (acc[c][2] + acc[c][3]);
            int j = c * 64 + lane;
            if (HAS_EXTRA) v += extra[(size_t)r * NOUT + j];
            if (HAS_BIAS) v += bias[j];
            if (RELU) v = fmaxf(v, 0.f);
            if (OUT_BF16)
                ((__hip_bfloat16*)out_)[(size_t)r * NOUT + j] = __float2bfloat16(v);
            else
                ((float*)out_)[(size_t)r * NOUT + j] = v;
        }
    }
}

// ---------------- decoder: 16-lane segment per edge, persistent ----------

__global__ __launch_bounds__(256) void decoder16_kernel(
    const int* __restrict__ src, const int* __restrict__ dst,
    const uint4* __restrict__ Za, const uint4* __restrict__ Zb,
    const float* __restrict__ db1, const float* __restrict__ dW2,
    const float* __restrict__ db2, float* __restrict__ pred,
    int Eobs, int nseg)
{
    int t = blockIdx.x * blockDim.x + threadIdx.x;
    int l = t & 15;
    int seg = t >> 4;
    float4 c1a = ((const float4*)db1)[2 * l];
    float4 c1b = ((const float4*)db1)[2 * l + 1];
    float4 w2a = ((const float4*)dW2)[2 * l];
    float4 w2b = ((const float4*)dW2)[2 * l + 1];
    float b2v = db2[0];

    for (int e = seg; e < Eobs; e += nseg) {
        int s = src[e], d = dst[e];
        uint4 ua = Za[(size_t)s * 16 + l];
        uint4 ub = Zb[(size_t)d * 16 + l];
        float acc;
        acc  = fmaxf(bf_lo(ua.x) + bf_lo(ub.x) + c1a.x, 0.f) * w2a.x;
        acc += fmaxf(bf_hi(ua.x) + bf_hi(ub.x) + c1a.y, 0.f) * w2a.y;
        acc += fmaxf(bf_lo(ua.y) + bf_lo(ub.y) + c1a.z, 0.f) * w2a.z;
        acc += fmaxf(bf_hi(ua.y) + bf_hi(ub.y) + c1a.w, 0.f) * w2a.w;
        acc += fmaxf(bf_lo(ua.z) + bf_lo(ub.z) + c1b.x, 0.f) * w2b.x;
        acc += fmaxf(bf_hi(ua.z) + bf_hi(ub.z) + c1b.y, 0.f) * w2b.y;
        acc += fmaxf(bf_lo(ua.w) + bf_lo(ub.w) + c1b.z, 0.f) * w2b.z;
        acc += fmaxf(bf_hi(ua.w) + bf_hi(ub.w) + c1b.w, 0.f) * w2b.w;
        #pragma unroll
        for (int o = 8; o > 0; o >>= 1) acc += __shfl_xor(acc, o, 64);
        if (l == 0) {
            float pv = acc + b2v;
            pred[e] = pv;
            pred[e + Eobs] = pv;
        }
    }
}

__global__ __launch_bounds__(256) void decoder_kernel(
    const int* __restrict__ src, const int* __restrict__ dst,
    const float* __restrict__ Z1a, const float* __restrict__ Z1b,
    const float* __restrict__ db1, const float* __restrict__ dW2,
    const float* __restrict__ db2, float* __restrict__ pred, int Eobs)
{
    int t = blockIdx.x * blockDim.x + threadIdx.x;
    int e = t >> 6;
    if (e >= Eobs) return;
    int lane = threadIdx.x & 63;
    int s = src[e], d = dst[e];
    float t0 = Z1a[(size_t)s * 128 + lane] + Z1b[(size_t)d * 128 + lane] + db1[lane];
    float t1 = Z1a[(size_t)s * 128 + lane + 64] + Z1b[(size_t)d * 128 + lane + 64] + db1[lane + 64];
    t0 = fmaxf(t0, 0.f);
    t1 = fmaxf(t1, 0.f);
    float acc = t0 * dW2[lane] + t1 * dW2[lane + 64];
    #pragma unroll
    for (int off = 32; off > 0; off >>= 1) acc += __shfl_xor(acc, off, 64);
    if (lane == 0) {
        float pv = acc + db2[0];
        pred[e] = pv;
        pred[e + Eobs] = pv;
    }
}

// ---------------- launch ----------------

extern "C" void kernel_launch(void* const* d_in, const int* in_sizes, int n_in,
                              void* d_out, int out_size, void* d_ws, size_t ws_size,
                              hipStream_t stream)
{
    const float* x     = (const float*)d_in[0];
    const int*   ei    = (const int*)d_in[1];
    const float* ew    = (const float*)d_in[2];
    const float* W1rel = (const float*)d_in[4];
    const float* b1    = (const float*)d_in[5];
    const float* W1rt  = (const float*)d_in[6];
    const float* W2rel = (const float*)d_in[7];
    const float* b2    = (const float*)d_in[8];
    const float* W2rt  = (const float*)d_in[9];
    const float* W3rel = (const float*)d_in[10];
    const float* b3    = (const float*)d_in[11];
    const float* W3rt  = (const float*)d_in[12];
    const float* dW1   = (const float*)d_in[13];
    const float* db1   = (const float*)d_in[14];
    const float* dW2   = (const float*)d_in[15];
    const float* db2   = (const float*)d_in[16];

    const int E    = in_sizes[2];
    const int N    = in_sizes[0] / 2;
    const int Eobs = E / 2;
    const int* src = ei;
    const int* dst = ei + E;

    // ws layout (floats):
    // [agg N*64][h1 N*128][h2 N*64][pbuf N*64][deg N][curs N][off N][p1 1024][p2 1024][csr E*2]
    float* agg  = (float*)d_ws;
    float* h1   = agg + (size_t)N * 64;
    float* h2   = h1 + (size_t)N * 128;
    float* pbuf = h2 + (size_t)N * 64;
    int*   deg  = (int*)(pbuf + (size_t)N * 64);
    int*   curs = deg + N;
    int*   off  = curs + N;
    int*   par1 = off + N;
    int*   par2 = par1 + 1024;
    float2* csr = (float2*)(par2 + 1024);

    size_t need = ((size_t)N * 320 + (size_t)N * 3 + 2048) * 4 + (size_t)E * 8;
    const bool use_csr = (ws_size >= need);

    // fast-build aliases (h1/h2 are dead during CSR build)
    uint2* bpos   = (uint2*)h1;     // E * 8 B <= N*128*4 B
    int*   ghist  = (int*)h2;
    const int nb      = (N + 127) >> 7;
    const int nchunks = cdiv(E, CHUNK);
    const int M       = nb * nchunks;
    int*   ghist_s = ghist + M;
    const bool fast_build = use_csr && nb <= 512 && N <= 65535 &&
                            (size_t)E * 2 <= (size_t)N * 128 &&
                            (size_t)M * 2 <= (size_t)N * 64;

    float* pred = (float*)d_out;
    float* z    = pred + E;
    __hip_bfloat16* Z1a16 = (__hip_bfloat16*)h1;   // h1 dead after layer-2
    __hip_bfloat16* Z1b16 = (__hip_bfloat16*)h2;   // h2 dead after layer-3
    __hip_bfloat16* pb16  = (__hip_bfloat16*)pbuf;

    const int nscan  = cdiv(N, 1024);
    const int nscanM = cdiv(M, 1024);

    if (use_csr) {
        // ---- CSR build ----
        if (fast_build) {
            p1_hist_kernel<<<nchunks, 256, 0, stream>>>(dst, ghist, E, nchunks, nb);
            // ghist_s = exclusive scan of ghist (bucket-major)
            scan_block_kernel<<<nscanM, 1024, 0, stream>>>(ghist, ghist_s, par1, M);
            scan_block_kernel<<<1, 1024, 0, stream>>>(par1, par2, nullptr, nscanM);
            scan_add_kernel<<<cdiv(M, 1024), 1024, 0, stream>>>(ghist_s, par2, M);
            p2_scatter_kernel<<<nchunks, 256, 0, stream>>>(src, dst, ew, ghist_s, bpos, E, nchunks, nb);
            p3_place_kernel<<<nb, 256, 0, stream>>>(bpos, ghist_s, deg, off, csr, E, nchunks, nb, N);
        } else {
            hipMemsetAsync(deg, 0, (size_t)N * 2 * sizeof(int), stream);  // deg + curs
            hist_kernel<<<cdiv(E, 256), 256, 0, stream>>>(dst, deg, E);
            scan_block_kernel<<<nscan, 1024, 0, stream>>>(deg, off, par1, N);
            scan_block_kernel<<<1, 1024, 0, stream>>>(par1, par2, nullptr, nscan);
            scan_add_kernel<<<cdiv(N, 1024), 1024, 0, stream>>>(off, par2, N);
            fill_csr_kernel<<<cdiv(E, 256), 256, 0, stream>>>(src, dst, ew, off, curs, csr, E);
        }

        // ---- layer 1 (fused CSR gather + expansion) ----
        layer1_fused_kernel<<<cdiv((long long)N * 64, 256), 256, 0, stream>>>(
            (const float2*)x, csr, off, deg, W1rel, W1rt, b1, h1, N);

        // ---- layer 2 (rel-projection in bf16 for the gather) ----
        gemm_small<128, 64, false, false, false, true><<<cdiv(N, 32), 256, 0, stream>>>(
            h1, N, W2rel, 64, 0, nullptr, nullptr, pb16);
        gather_b16_kernel<<<cdiv((long long)N * 64, 256), 256, 0, stream>>>(
            csr, off, deg, (const __hip_bfloat162*)pb16, agg, N);
        gemm_small<128, 64, true, true, true, false><<<cdiv(N, 32), 256, 0, stream>>>(
            h1, N, W2rt, 64, 0, b2, agg, h2);

        // ---- layer 3 ----
        gemm_small<64, 64, false, false, false, true><<<cdiv(N, 32), 256, 0, stream>>>(
            h2, N, W3rel, 64, 0, nullptr, nullptr, pb16);
        gather_b16_kernel<<<cdiv((long long)N * 64, 256), 256, 0, stream>>>(
            csr, off, deg, (const __hip_bfloat162*)pb16, agg, N);
        gemm_small<64, 64, false, true, true, false><<<cdiv(N, 32), 256, 0, stream>>>(
            h2, N, W3rt, 64, 0, b3, agg, z);

        // ---- decoder (bf16 tables, 16-lane segments, persistent) ----
        gemm_small<64, 128, false, false, false, true><<<cdiv(N, 32), 256, 0, stream>>>(
            z, N, dW1, 128, 0, nullptr, nullptr, Z1a16);
        gemm_small<64, 128, false, false, false, true><<<cdiv(N, 32), 256, 0, stream>>>(
            z, N, dW1, 128, 64, nullptr, nullptr, Z1b16);
        int dblocks = 2048;
        if (dblocks > cdiv((long long)Eobs * 16, 256)) dblocks = cdiv((long long)Eobs * 16, 256);
        int nseg = dblocks * 16;
        decoder16_kernel<<<dblocks, 256, 0, stream>>>(
            src, dst, (const uint4*)Z1a16, (const uint4*)Z1b16,
            db1, dW2, db2, pred, Eobs, nseg);
    } else {
        // ---- fallback: atomic scatter path (fp32 throughout) ----
        float* Z1a = h1;
        float* Z1b = h2;
        hipMemsetAsync(agg, 0, (size_t)N * 2 * sizeof(float), stream);
        scatter_f2_kernel<<<cdiv(E, 256), 256, 0, stream>>>(src, dst, ew, x, agg, E);
        layer1_kernel<<<cdiv((long long)N * 128, 256), 256, 0, stream>>>(x, agg, W1rel, W1rt, b1, h1, N);

        gemm_small<128, 64, false, false, false, false><<<cdiv(N, 32), 256, 0, stream>>>(
            h1, N, W2rel, 64, 0, nullptr, nullptr, pbuf);
        hipMemsetAsync(agg, 0, (size_t)N * 64 * sizeof(float), stream);
        scatter_f64_kernel<<<cdiv((long long)E * 64, 256), 256, 0, stream>>>(src, dst, ew, pbuf, agg, E);
        gemm_small<128, 64, true, true, true, false><<<cdiv(N, 32), 256, 0, stream>>>(
            h1, N, W2rt, 64, 0, b2, agg, h2);

        gemm_small<64, 64, false, false, false, false><<<cdiv(N, 32), 256, 0, stream>>>(
            h2, N, W3rel, 64, 0, nullptr, nullptr, pbuf);
        hipMemsetAsync(agg, 0, (size_t)N * 64 * sizeof(float), stream);
        scatter_f64_kernel<<<cdiv((long long)E * 64, 256), 256, 0, stream>>>(src, dst, ew, pbuf, agg, E);
        gemm_small<64, 64, false, true, true, false><<<cdiv(N, 32), 256, 0, stream>>>(
            h2, N, W3rt, 64, 0, b3, agg, z);

        gemm_small<64, 128, false, false, false, false><<<cdiv(N, 32), 256, 0, stream>>>(
            z, N, dW1, 128, 0, nullptr, nullptr, Z1a);
        gemm_small<64, 128, false, false, false, false><<<cdiv(N, 32), 256, 0, stream>>>(
            z, N, dW1, 128, 64, nullptr, nullptr, Z1b);
        decoder_kernel<<<cdiv((long long)Eobs * 64, 256), 256, 0, stream>>>(
            src, dst, Z1a, Z1b, db1, dW2, db2, pred, Eobs);
    }
}

// Round 8
// 397.098 us; speedup vs baseline: 3.4311x; 1.3742x over previous
//
#include <hip/hip_runtime.h>
#include <hip/hip_bf16.h>

static inline int cdiv(long long a, long long b) { return (int)((a + b - 1) / b); }

__device__ inline float bf_lo(unsigned u) { return __uint_as_float(u << 16); }
__device__ inline float bf_hi(unsigned u) { return __uint_as_float(u & 0xffff0000u); }

typedef short bf16x8 __attribute__((ext_vector_type(8)));
typedef float f32x4 __attribute__((ext_vector_type(4)));

#define CHUNK 8192

// ---------------- weight prep: fp32 -> bf16, transposed Wt[n][k] ----------
// layout (bf16 elems): [0]W2rel_t(64x128) [8192]W2rt_t(64x128)
// [16384]W3rel_t(64x64) [20480]W3rt_t(64x64) [24576]dW1a_t(128x64) [32768]dW1b_t(128x64)
__global__ __launch_bounds__(256) void prep_weights_kernel(
    const float* __restrict__ W2rel, const float* __restrict__ W2rt,
    const float* __restrict__ W3rel, const float* __restrict__ W3rt,
    const float* __restrict__ dW1, __hip_bfloat16* __restrict__ wt)
{
    int i = blockIdx.x * 256 + threadIdx.x;
    if (i >= 40960) return;
    float v;
    if (i < 8192)       { int n = i >> 7, k = i & 127;              v = W2rel[k * 64 + n]; }
    else if (i < 16384) { int j = i - 8192;  int n = j >> 7, k = j & 127; v = W2rt[k * 64 + n]; }
    else if (i < 20480) { int j = i - 16384; int n = j >> 6, k = j & 63;  v = W3rel[k * 64 + n]; }
    else if (i < 24576) { int j = i - 20480; int n = j >> 6, k = j & 63;  v = W3rt[k * 64 + n]; }
    else if (i < 32768) { int j = i - 24576; int n = j >> 6, k = j & 63;  v = dW1[k * 128 + n]; }
    else                { int j = i - 32768; int n = j >> 6, k = j & 63;  v = dW1[(64 + k) * 128 + n]; }
    wt[i] = __float2bfloat16(v);
}

// ---------------- MFMA dense GEMM: 16 rows/block, wave = 16-col strip -----
// A: M x K bf16 row-major; Wt: NOUT x K bf16 (transposed weights).
// EPI 0: out bf16.  EPI 1: +extra+bias, relu, out bf16.
// EPI 2: +extra+bias, out fp32 AND bf16.
template <int K, int NOUT, int EPI>
__global__ __launch_bounds__(256) void mfma_gemm_kernel(
    const __hip_bfloat16* __restrict__ A,
    const __hip_bfloat16* __restrict__ Wt,
    const float* __restrict__ bias,
    const float* __restrict__ extra,
    __hip_bfloat16* __restrict__ outb,
    float* __restrict__ outf, int M)
{
    constexpr int KF = K / 32;
    constexpr int SPW = NOUT / 64;   // strips per wave
    const int wv = threadIdx.x >> 6;
    const int lane = threadIdx.x & 63;
    const int m = lane & 15, q = lane >> 4;
    const int row0 = blockIdx.x * 16;
    const int arow = row0 + m;

    // A fragments: lane holds A[m=lane&15][k = q*8 + j] -- 16B contiguous
    bf16x8 af[KF];
    #pragma unroll
    for (int kf = 0; kf < KF; kf++)
        af[kf] = *(const bf16x8*)(A + (size_t)arow * K + kf * 32 + q * 8);

    #pragma unroll
    for (int s = 0; s < SPW; s++) {
        const int col = (wv * SPW + s) * 16 + m;   // B n-index = lane&15
        f32x4 acc = {0.f, 0.f, 0.f, 0.f};
        #pragma unroll
        for (int kf = 0; kf < KF; kf++) {
            bf16x8 bf = *(const bf16x8*)(Wt + (size_t)col * K + kf * 32 + q * 8);
            acc = __builtin_amdgcn_mfma_f32_16x16x32_bf16(af[kf], bf, acc, 0, 0, 0);
        }
        // C/D: col = lane&15, row = q*4 + r   [m89-verified]
        #pragma unroll
        for (int r = 0; r < 4; r++) {
            int rr = row0 + q * 4 + r;
            size_t idx = (size_t)rr * NOUT + col;
            float v = acc[r];
            if (EPI >= 1) v += extra[idx] + bias[col];
            if (EPI == 1) v = fmaxf(v, 0.f);
            if (EPI == 2) outf[idx] = v;
            outb[idx] = __float2bfloat16(v);
        }
    }
}

// ---------------- bucketed CSR build (3 phases) ----------------

__global__ __launch_bounds__(256) void p1_hist_kernel(
    const int* __restrict__ dst, int* __restrict__ ghist,
    int E, int nchunks, int nb)
{
    __shared__ int sh[512];
    int c = blockIdx.x;
    for (int i = threadIdx.x; i < nb; i += 256) sh[i] = 0;
    __syncthreads();
    int base = c * CHUNK;
    int end = min(base + CHUNK, E);
    for (int i = base + threadIdx.x; i < end; i += 256)
        atomicAdd(&sh[dst[i] >> 7], 1);
    __syncthreads();
    for (int i = threadIdx.x; i < nb; i += 256)
        ghist[i * nchunks + c] = sh[i];
}

__global__ __launch_bounds__(256) void p2_scatter_kernel(
    const int* __restrict__ src, const int* __restrict__ dst,
    const float* __restrict__ ew, const int* __restrict__ gs,
    uint2* __restrict__ bpos, int E, int nchunks, int nb)
{
    __shared__ int cur[512];
    int c = blockIdx.x;
    for (int i = threadIdx.x; i < nb; i += 256) cur[i] = gs[i * nchunks + c];
    __syncthreads();
    int base = c * CHUNK;
    int end = min(base + CHUNK, E);
    for (int i = base + threadIdx.x; i < end; i += 256) {
        int d = dst[i];
        int pos = atomicAdd(&cur[d >> 7], 1);
        bpos[pos] = make_uint2(((unsigned)d << 16) | (unsigned)src[i],
                               __float_as_uint(ew[i]));
    }
}

__global__ __launch_bounds__(256) void p3_place_kernel(
    const uint2* __restrict__ bpos, const int* __restrict__ gs,
    int* __restrict__ deg, int* __restrict__ off,
    float2* __restrict__ csr, int E, int nchunks, int nb, int N)
{
    __shared__ int cnt[128];
    __shared__ int pos[128];
    int b = blockIdx.x;
    int nodebase = b << 7;
    if (threadIdx.x < 128) cnt[threadIdx.x] = 0;
    __syncthreads();
    int begin = gs[b * nchunks];
    int bend = (b + 1 < nb) ? gs[(b + 1) * nchunks] : E;
    for (int i = begin + threadIdx.x; i < bend; i += 256)
        atomicAdd(&cnt[(bpos[i].x >> 16) - nodebase], 1);
    __syncthreads();
    int v = 0;
    if (threadIdx.x < 128) { v = cnt[threadIdx.x]; pos[threadIdx.x] = v; }
    __syncthreads();
    #pragma unroll
    for (int ofs = 1; ofs < 128; ofs <<= 1) {
        int t = 0;
        if (threadIdx.x < 128 && threadIdx.x >= ofs) t = pos[threadIdx.x - ofs];
        __syncthreads();
        if (threadIdx.x < 128) pos[threadIdx.x] += t;
        __syncthreads();
    }
    if (threadIdx.x < 128) {
        int ex = begin + pos[threadIdx.x] - v;
        int n = nodebase + threadIdx.x;
        if (n < N) { off[n] = ex; deg[n] = v; }
        cnt[threadIdx.x] = ex;
    }
    __syncthreads();
    for (int i = begin + threadIdx.x; i < bend; i += 256) {
        uint2 en = bpos[i];
        int d = en.x >> 16;
        int p = atomicAdd(&cnt[d - nodebase], 1);
        csr[p] = make_float2(__int_as_float((int)(en.x & 0xffffu)),
                             __uint_as_float(en.y));
    }
}

// ---------------- scan helpers ----------------

__global__ __launch_bounds__(1024) void scan_block_kernel(
    const int* __restrict__ in, int* __restrict__ out,
    int* __restrict__ partials, int N)
{
    __shared__ int sdata[1024];
    const int tid = threadIdx.x;
    const int i = blockIdx.x * 1024 + tid;
    int v = (i < N) ? in[i] : 0;
    sdata[tid] = v;
    __syncthreads();
    #pragma unroll
    for (int ofs = 1; ofs < 1024; ofs <<= 1) {
        int t = (tid >= ofs) ? sdata[tid - ofs] : 0;
        __syncthreads();
        sdata[tid] += t;
        __syncthreads();
    }
    if (i < N) out[i] = sdata[tid] - v;
    if (partials && tid == 1023) partials[blockIdx.x] = sdata[1023];
}

__global__ __launch_bounds__(1024) void scan_add_kernel(
    int* __restrict__ off, const int* __restrict__ blockoff, int N)
{
    int i = blockIdx.x * blockDim.x + threadIdx.x;
    if (i < N) off[i] += blockoff[i >> 10];
}

// ---------------- fallback CSR build ----------------

__global__ __launch_bounds__(256) void hist_kernel(
    const int* __restrict__ dst, int* __restrict__ deg, int E)
{
    int e = blockIdx.x * blockDim.x + threadIdx.x;
    if (e < E) atomicAdd(&deg[dst[e]], 1);
}

__global__ __launch_bounds__(256) void fill_csr_kernel(
    const int* __restrict__ src, const int* __restrict__ dst,
    const float* __restrict__ ew, const int* __restrict__ off,
    int* __restrict__ cursor, float2* __restrict__ csr, int E)
{
    int e = blockIdx.x * blockDim.x + threadIdx.x;
    if (e >= E) return;
    int d = dst[e];
    int i = off[d] + atomicAdd(&cursor[d], 1);
    csr[i] = make_float2(__int_as_float(src[e]), ew[e]);
}

// ---------------- fused layer 1: CSR gather + expand to 128 (bf16 out) ----

__global__ __launch_bounds__(256) void layer1_fused_kernel(
    const float2* __restrict__ x2, const float2* __restrict__ csr,
    const int* __restrict__ off, const int* __restrict__ deg,
    const float* __restrict__ W1rel, const float* __restrict__ W1rt,
    const float* __restrict__ b1, __hip_bfloat16* __restrict__ h1b, int N)
{
    int t = blockIdx.x * blockDim.x + threadIdx.x;
    int n = t >> 6;
    if (n >= N) return;
    int lane = t & 63;
    int beg = off[n], cnt = deg[n];
    float a0 = 0.f, a1 = 0.f;
    for (int i = lane; i < cnt; i += 64) {
        float2 c = csr[beg + i];
        float2 xs = x2[__float_as_int(c.x)];
        a0 = fmaf(c.y, xs.x, a0);
        a1 = fmaf(c.y, xs.y, a1);
    }
    #pragma unroll
    for (int o = 32; o > 0; o >>= 1) {
        a0 += __shfl_xor(a0, o, 64);
        a1 += __shfl_xor(a1, o, 64);
    }
    float2 xn = x2[n];
    float v0 = b1[lane] + a0 * W1rel[lane] + a1 * W1rel[128 + lane]
             + xn.x * W1rt[lane] + xn.y * W1rt[128 + lane];
    float v1 = b1[64 + lane] + a0 * W1rel[64 + lane] + a1 * W1rel[192 + lane]
             + xn.x * W1rt[64 + lane] + xn.y * W1rt[192 + lane];
    h1b[(size_t)n * 128 + lane]      = __float2bfloat16(fmaxf(v0, 0.f));
    h1b[(size_t)n * 128 + 64 + lane] = __float2bfloat16(fmaxf(v1, 0.f));
}

// ---------------- gather aggregation, bf16 p-table ----------------

__global__ __launch_bounds__(256) void gather_b16_kernel(
    const float2* __restrict__ csr, const int* __restrict__ off,
    const int* __restrict__ deg, const __hip_bfloat162* __restrict__ p,
    float* __restrict__ agg, int N)
{
    int t = blockIdx.x * blockDim.x + threadIdx.x;
    int n = t >> 6;
    if (n >= N) return;
    int lane = t & 63;
    int half = lane >> 5;
    int fp = lane & 31;
    int beg = off[n], cnt = deg[n];
    float a0 = 0.f, a1 = 0.f;
    int i = half;
    for (; i + 2 < cnt; i += 4) {
        float2 c0 = csr[beg + i];
        float2 c1 = csr[beg + i + 2];
        float2 v0 = __bfloat1622float2(p[(size_t)__float_as_int(c0.x) * 32 + fp]);
        float2 v1 = __bfloat1622float2(p[(size_t)__float_as_int(c1.x) * 32 + fp]);
        a0 = fmaf(c0.y, v0.x, a0); a1 = fmaf(c0.y, v0.y, a1);
        a0 = fmaf(c1.y, v1.x, a0); a1 = fmaf(c1.y, v1.y, a1);
    }
    for (; i < cnt; i += 2) {
        float2 c = csr[beg + i];
        float2 v = __bfloat1622float2(p[(size_t)__float_as_int(c.x) * 32 + fp]);
        a0 = fmaf(c.y, v.x, a0); a1 = fmaf(c.y, v.y, a1);
    }
    a0 += __shfl_xor(a0, 32, 64);
    a1 += __shfl_xor(a1, 32, 64);
    if (half == 0)
        ((float2*)agg)[(size_t)n * 32 + fp] = make_float2(a0, a1);
}

// ---------------- fallback atomic path kernels ----------------

__global__ __launch_bounds__(256) void scatter_f64_kernel(
    const int* __restrict__ src, const int* __restrict__ dst,
    const float* __restrict__ ew, const float* __restrict__ p,
    float* __restrict__ agg, int E)
{
    int t = blockIdx.x * blockDim.x + threadIdx.x;
    int e = t >> 6;
    if (e >= E) return;
    int j = t & 63;
    atomicAdd(&agg[(size_t)dst[e] * 64 + j], p[(size_t)src[e] * 64 + j] * ew[e]);
}

__global__ __launch_bounds__(256) void scatter_f2_kernel(
    const int* __restrict__ src, const int* __restrict__ dst,
    const float* __restrict__ ew, const float* __restrict__ x,
    float* __restrict__ agg, int E)
{
    int e = blockIdx.x * blockDim.x + threadIdx.x;
    if (e >= E) return;
    int s = src[e], d = dst[e];
    float w = ew[e];
    atomicAdd(&agg[d * 2 + 0], x[s * 2 + 0] * w);
    atomicAdd(&agg[d * 2 + 1], x[s * 2 + 1] * w);
}

__global__ __launch_bounds__(256) void layer1_kernel(
    const float* __restrict__ x, const float* __restrict__ agg,
    const float* __restrict__ W1rel, const float* __restrict__ W1root,
    const float* __restrict__ b1, float* __restrict__ h1, int N)
{
    int t = blockIdx.x * blockDim.x + threadIdx.x;
    if (t >= N * 128) return;
    int n = t >> 7, j = t & 127;
    float v = b1[j]
        + agg[n * 2 + 0] * W1rel[j] + agg[n * 2 + 1] * W1rel[128 + j]
        + x[n * 2 + 0] * W1root[j] + x[n * 2 + 1] * W1root[128 + j];
    h1[t] = fmaxf(v, 0.f);
}

template <int K, int NOUT, bool RELU, bool HAS_EXTRA, bool HAS_BIAS, bool OUT_BF16>
__global__ __launch_bounds__(256) void gemm_small(
    const float* __restrict__ in, int M,
    const float* __restrict__ W, int ldw, int woff,
    const float* __restrict__ bias,
    const float* __restrict__ extra,
    void* __restrict__ out_)
{
    constexpr int CPT = NOUT / 64;
    __shared__ float sW[K * NOUT];
    __shared__ float sX[4][K];
    const int tid = threadIdx.x;
    const int lane = tid & 63;
    const int wv = tid >> 6;
    for (int idx = tid; idx < K * NOUT; idx += 256) {
        int k = idx / NOUT;
        int j = idx - k * NOUT;
        sW[idx] = W[(size_t)(k + woff) * ldw + j];
    }
    __syncthreads();
    const int ROWS = 32;
    int r0 = blockIdx.x * ROWS;
    for (int rr = wv; rr < ROWS; rr += 4) {
        int r = r0 + rr;
        if (r >= M) break;
        #pragma unroll
        for (int kk = lane; kk < K; kk += 64) sX[wv][kk] = in[(size_t)r * K + kk];
        float acc[CPT][4];
        #pragma unroll
        for (int c = 0; c < CPT; c++)
            #pragma unroll
            for (int u = 0; u < 4; u++) acc[c][u] = 0.f;
        #pragma unroll
        for (int k = 0; k < K; k += 4) {
            #pragma unroll
            for (int u = 0; u < 4; u++) {
                float xv = sX[wv][k + u];
                #pragma unroll
                for (int c = 0; c < CPT; c++)
                    acc[c][u] = fmaf(xv, sW[(k + u) * NOUT + c * 64 + lane], acc[c][u]);
            }
        }
        #pragma unroll
        for (int c = 0; c < CPT; c++) {
            float v = (acc[c][0] + acc[c][1]) + (acc[c][2] + acc[c][3]);
            int j = c * 64 + lane;
            if (HAS_EXTRA) v += extra[(size_t)r * NOUT + j];
            if (HAS_BIAS) v += bias[j];
            if (RELU) v = fmaxf(v, 0.f);
            if (OUT_BF16)
                ((__hip_bfloat16*)out_)[(size_t)r * NOUT + j] = __float2bfloat16(v);
            else
                ((float*)out_)[(size_t)r * NOUT + j] = v;
        }
    }
}

// ---------------- decoder: 16-lane segment per edge, persistent ----------

__global__ __launch_bounds__(256) void decoder16_kernel(
    const int* __restrict__ src, const int* __restrict__ dst,
    const uint4* __restrict__ Za, const uint4* __restrict__ Zb,
    const float* __restrict__ db1, const float* __restrict__ dW2,
    const float* __restrict__ db2, float* __restrict__ pred,
    int Eobs, int nseg)
{
    int t = blockIdx.x * blockDim.x + threadIdx.x;
    int l = t & 15;
    int seg = t >> 4;
    float4 c1a = ((const float4*)db1)[2 * l];
    float4 c1b = ((const float4*)db1)[2 * l + 1];
    float4 w2a = ((const float4*)dW2)[2 * l];
    float4 w2b = ((const float4*)dW2)[2 * l + 1];
    float b2v = db2[0];

    for (int e = seg; e < Eobs; e += nseg) {
        int s = src[e], d = dst[e];
        uint4 ua = Za[(size_t)s * 16 + l];
        uint4 ub = Zb[(size_t)d * 16 + l];
        float acc;
        acc  = fmaxf(bf_lo(ua.x) + bf_lo(ub.x) + c1a.x, 0.f) * w2a.x;
        acc += fmaxf(bf_hi(ua.x) + bf_hi(ub.x) + c1a.y, 0.f) * w2a.y;
        acc += fmaxf(bf_lo(ua.y) + bf_lo(ub.y) + c1a.z, 0.f) * w2a.z;
        acc += fmaxf(bf_hi(ua.y) + bf_hi(ub.y) + c1a.w, 0.f) * w2a.w;
        acc += fmaxf(bf_lo(ua.z) + bf_lo(ub.z) + c1b.x, 0.f) * w2b.x;
        acc += fmaxf(bf_hi(ua.z) + bf_hi(ub.z) + c1b.y, 0.f) * w2b.y;
        acc += fmaxf(bf_lo(ua.w) + bf_lo(ub.w) + c1b.z, 0.f) * w2b.z;
        acc += fmaxf(bf_hi(ua.w) + bf_hi(ub.w) + c1b.w, 0.f) * w2b.w;
        #pragma unroll
        for (int o = 8; o > 0; o >>= 1) acc += __shfl_xor(acc, o, 64);
        if (l == 0) {
            float pv = acc + b2v;
            pred[e] = pv;
            pred[e + Eobs] = pv;
        }
    }
}

__global__ __launch_bounds__(256) void decoder_kernel(
    const int* __restrict__ src, const int* __restrict__ dst,
    const float* __restrict__ Z1a, const float* __restrict__ Z1b,
    const float* __restrict__ db1, const float* __restrict__ dW2,
    const float* __restrict__ db2, float* __restrict__ pred, int Eobs)
{
    int t = blockIdx.x * blockDim.x + threadIdx.x;
    int e = t >> 6;
    if (e >= Eobs) return;
    int lane = threadIdx.x & 63;
    int s = src[e], d = dst[e];
    float t0 = Z1a[(size_t)s * 128 + lane] + Z1b[(size_t)d * 128 + lane] + db1[lane];
    float t1 = Z1a[(size_t)s * 128 + lane + 64] + Z1b[(size_t)d * 128 + lane + 64] + db1[lane + 64];
    t0 = fmaxf(t0, 0.f);
    t1 = fmaxf(t1, 0.f);
    float acc = t0 * dW2[lane] + t1 * dW2[lane + 64];
    #pragma unroll
    for (int off = 32; off > 0; off >>= 1) acc += __shfl_xor(acc, off, 64);
    if (lane == 0) {
        float pv = acc + db2[0];
        pred[e] = pv;
        pred[e + Eobs] = pv;
    }
}

// ---------------- launch ----------------

extern "C" void kernel_launch(void* const* d_in, const int* in_sizes, int n_in,
                              void* d_out, int out_size, void* d_ws, size_t ws_size,
                              hipStream_t stream)
{
    const float* x     = (const float*)d_in[0];
    const int*   ei    = (const int*)d_in[1];
    const float* ew    = (const float*)d_in[2];
    const float* W1rel = (const float*)d_in[4];
    const float* b1    = (const float*)d_in[5];
    const float* W1rt  = (const float*)d_in[6];
    const float* W2rel = (const float*)d_in[7];
    const float* b2    = (const float*)d_in[8];
    const float* W2rt  = (const float*)d_in[9];
    const float* W3rel = (const float*)d_in[10];
    const float* b3    = (const float*)d_in[11];
    const float* W3rt  = (const float*)d_in[12];
    const float* dW1   = (const float*)d_in[13];
    const float* db1   = (const float*)d_in[14];
    const float* dW2   = (const float*)d_in[15];
    const float* db2   = (const float*)d_in[16];

    const int E    = in_sizes[2];
    const int N    = in_sizes[0] / 2;
    const int Eobs = E / 2;
    const int* src = ei;
    const int* dst = ei + E;

    // ws regions (units = floats):
    // R0 agg N*64 (build-time: ghist/ghist_s) | R1 h1b/Z1a N*64 | R2 pb/zb N*32
    // R3 h2b N*32 | R4 Z1b / bpos N*64 | deg N | off N | par 2048 | wt 20480 | csr E*2
    float* agg  = (float*)d_ws;
    float* R1   = agg + (size_t)N * 64;
    float* R2   = R1 + (size_t)N * 64;
    float* R3   = R2 + (size_t)N * 32;
    float* R4   = R3 + (size_t)N * 32;
    int*   deg  = (int*)(R4 + (size_t)N * 64);
    int*   off  = deg + N;
    int*   par1 = off + N;
    int*   par2 = par1 + 1024;
    float* wtf  = (float*)(par2 + 1024);           // 20480 floats = 40960 bf16
    __hip_bfloat16* wt = (__hip_bfloat16*)wtf;
    float2* csr = (float2*)(wtf + 20480);          // FIXED: offset in float units

    __hip_bfloat16* h1b   = (__hip_bfloat16*)R1;
    __hip_bfloat16* Z1a16 = (__hip_bfloat16*)R1;
    __hip_bfloat16* pb16  = (__hip_bfloat16*)R2;
    __hip_bfloat16* zb16  = (__hip_bfloat16*)R2;
    __hip_bfloat16* h2b   = (__hip_bfloat16*)R3;
    __hip_bfloat16* Z1b16 = (__hip_bfloat16*)R4;
    uint2* bpos  = (uint2*)R4;
    int*   ghist = (int*)agg;

    const int nb      = (N + 127) >> 7;
    const int nchunks = cdiv(E, CHUNK);
    const int M       = nb * nchunks;
    int* ghist_s = ghist + M;

    size_t need = ((size_t)N * 258 + 22528 + (size_t)E * 2) * 4;
    const bool fast = (ws_size >= need) && nb <= 512 && N <= 65535 &&
                      (N % 16 == 0) &&
                      (size_t)E * 2 <= (size_t)N * 64 &&      // bpos fits R4
                      (size_t)M * 2 <= (size_t)N * 64;        // ghists fit R0

    float* pred = (float*)d_out;
    float* z    = pred + E;

    const int nscanM = cdiv(M, 1024);
    const int gblocks = N / 16;

    // weight offsets (bf16 elems)
    __hip_bfloat16* wt2rel = wt;
    __hip_bfloat16* wt2rt  = wt + 8192;
    __hip_bfloat16* wt3rel = wt + 16384;
    __hip_bfloat16* wt3rt  = wt + 20480;
    __hip_bfloat16* wtd1a  = wt + 24576;
    __hip_bfloat16* wtd1b  = wt + 32768;

    if (fast) {
        prep_weights_kernel<<<160, 256, 0, stream>>>(W2rel, W2rt, W3rel, W3rt, dW1, wt);

        // ---- CSR build ----
        p1_hist_kernel<<<nchunks, 256, 0, stream>>>(dst, ghist, E, nchunks, nb);
        scan_block_kernel<<<nscanM, 1024, 0, stream>>>(ghist, ghist_s, par1, M);
        scan_block_kernel<<<1, 1024, 0, stream>>>(par1, par2, nullptr, nscanM);
        scan_add_kernel<<<cdiv(M, 1024), 1024, 0, stream>>>(ghist_s, par2, M);
        p2_scatter_kernel<<<nchunks, 256, 0, stream>>>(src, dst, ew, ghist_s, bpos, E, nchunks, nb);
        p3_place_kernel<<<nb, 256, 0, stream>>>(bpos, ghist_s, deg, off, csr, E, nchunks, nb, N);

        // ---- layer 1 ----
        layer1_fused_kernel<<<cdiv((long long)N * 64, 256), 256, 0, stream>>>(
            (const float2*)x, csr, off, deg, W1rel, W1rt, b1, h1b, N);

        // ---- layer 2 ----
        mfma_gemm_kernel<128, 64, 0><<<gblocks, 256, 0, stream>>>(
            h1b, wt2rel, nullptr, nullptr, pb16, nullptr, N);
        gather_b16_kernel<<<cdiv((long long)N * 64, 256), 256, 0, stream>>>(
            csr, off, deg, (const __hip_bfloat162*)pb16, agg, N);
        mfma_gemm_kernel<128, 64, 1><<<gblocks, 256, 0, stream>>>(
            h1b, wt2rt, b2, agg, h2b, nullptr, N);

        // ---- layer 3 ----
        mfma_gemm_kernel<64, 64, 0><<<gblocks, 256, 0, stream>>>(
            h2b, wt3rel, nullptr, nullptr, pb16, nullptr, N);
        gather_b16_kernel<<<cdiv((long long)N * 64, 256), 256, 0, stream>>>(
            csr, off, deg, (const __hip_bfloat162*)pb16, agg, N);
        mfma_gemm_kernel<64, 64, 2><<<gblocks, 256, 0, stream>>>(
            h2b, wt3rt, b3, agg, zb16, z, N);

        // ---- decoder ----
        mfma_gemm_kernel<64, 128, 0><<<gblocks, 256, 0, stream>>>(
            zb16, wtd1a, nullptr, nullptr, Z1a16, nullptr, N);
        mfma_gemm_kernel<64, 128, 0><<<gblocks, 256, 0, stream>>>(
            zb16, wtd1b, nullptr, nullptr, Z1b16, nullptr, N);
        int dblocks = 2048;
        if (dblocks > cdiv((long long)Eobs * 16, 256)) dblocks = cdiv((long long)Eobs * 16, 256);
        int nseg = dblocks * 16;
        decoder16_kernel<<<dblocks, 256, 0, stream>>>(
            src, dst, (const uint4*)Z1a16, (const uint4*)Z1b16,
            db1, dW2, db2, pred, Eobs, nseg);
    } else {
        // ---- fallback: atomic scatter path (fp32 throughout) ----
        float* h1   = agg + (size_t)N * 64;
        float* h2   = h1 + (size_t)N * 128;
        float* pbuf = h2 + (size_t)N * 64;
        float* Z1a = h1;
        float* Z1b = h2;
        hipMemsetAsync(agg, 0, (size_t)N * 2 * sizeof(float), stream);
        scatter_f2_kernel<<<cdiv(E, 256), 256, 0, stream>>>(src, dst, ew, x, agg, E);
        layer1_kernel<<<cdiv((long long)N * 128, 256), 256, 0, stream>>>(x, agg, W1rel, W1rt, b1, h1, N);

        gemm_small<128, 64, false, false, false, false><<<cdiv(N, 32), 256, 0, stream>>>(
            h1, N, W2rel, 64, 0, nullptr, nullptr, pbuf);
        hipMemsetAsync(agg, 0, (size_t)N * 64 * sizeof(float), stream);
        scatter_f64_kernel<<<cdiv((long long)E * 64, 256), 256, 0, stream>>>(src, dst, ew, pbuf, agg, E);
        gemm_small<128, 64, true, true, true, false><<<cdiv(N, 32), 256, 0, stream>>>(
            h1, N, W2rt, 64, 0, b2, agg, h2);

        gemm_small<64, 64, false, false, false, false><<<cdiv(N, 32), 256, 0, stream>>>(
            h2, N, W3rel, 64, 0, nullptr, nullptr, pbuf);
        hipMemsetAsync(agg, 0, (size_t)N * 64 * sizeof(float), stream);
        scatter_f64_kernel<<<cdiv((long long)E * 64, 256), 256, 0, stream>>>(src, dst, ew, pbuf, agg, E);
        gemm_small<64, 64, false, true, true, false><<<cdiv(N, 32), 256, 0, stream>>>(
            h2, N, W3rt, 64, 0, b3, agg, z);

        gemm_small<64, 128, false, false, false, false><<<cdiv(N, 32), 256, 0, stream>>>(
            z, N, dW1, 128, 0, nullptr, nullptr, Z1a);
        gemm_small<64, 128, false, false, false, false><<<cdiv(N, 32), 256, 0, stream>>>(
            z, N, dW1, 128, 64, nullptr, nullptr, Z1b);
        decoder_kernel<<<cdiv((long long)Eobs * 64, 256), 256, 0, stream>>>(
            src, dst, Z1a, Z1b, db1, dW2, db2, pred, Eobs);
    }
}

// Round 9
// 391.245 us; speedup vs baseline: 3.4824x; 1.0150x over previous
//
#include <hip/hip_runtime.h>
#include <hip/hip_bf16.h>

static inline int cdiv(long long a, long long b) { return (int)((a + b - 1) / b); }

__device__ inline float bf_lo(unsigned u) { return __uint_as_float(u << 16); }
__device__ inline float bf_hi(unsigned u) { return __uint_as_float(u & 0xffff0000u); }

typedef short bf16x8 __attribute__((ext_vector_type(8)));
typedef float f32x4 __attribute__((ext_vector_type(4)));

#define CHUNK 8192

// ---------------- P1 + weight prep fused ----------------
// blocks [0, nchunks): per-chunk LDS histogram over 128-node buckets.
// blocks [nchunks, nchunks+160): fp32->bf16 transposed weight tables.
// wt layout (bf16): [0]W2rel_t(64x128) [8192]W2rt_t(64x128) [16384]W3rel_t(64x64)
// [20480]W3rt_t(64x64) [24576]dW1a_t(128x64) [32768]dW1b_t(128x64)
__global__ __launch_bounds__(256) void p1_prep_kernel(
    const int* __restrict__ dst, int* __restrict__ ghist,
    int E, int nchunks, int nb,
    const float* __restrict__ W2rel, const float* __restrict__ W2rt,
    const float* __restrict__ W3rel, const float* __restrict__ W3rt,
    const float* __restrict__ dW1, __hip_bfloat16* __restrict__ wt)
{
    __shared__ int sh[512];
    if (blockIdx.x < (unsigned)nchunks) {
        int c = blockIdx.x;
        for (int i = threadIdx.x; i < nb; i += 256) sh[i] = 0;
        __syncthreads();
        int base = c * CHUNK;
        int end = min(base + CHUNK, E);
        for (int i = base + threadIdx.x; i < end; i += 256)
            atomicAdd(&sh[dst[i] >> 7], 1);
        __syncthreads();
        for (int i = threadIdx.x; i < nb; i += 256)
            ghist[i * nchunks + c] = sh[i];
    } else {
        int i = (blockIdx.x - nchunks) * 256 + threadIdx.x;
        if (i >= 40960) return;
        float v;
        if (i < 8192)       { int n = i >> 7, k = i & 127;               v = W2rel[k * 64 + n]; }
        else if (i < 16384) { int j = i - 8192;  int n = j >> 7, k = j & 127; v = W2rt[k * 64 + n]; }
        else if (i < 20480) { int j = i - 16384; int n = j >> 6, k = j & 63;  v = W3rel[k * 64 + n]; }
        else if (i < 24576) { int j = i - 20480; int n = j >> 6, k = j & 63;  v = W3rt[k * 64 + n]; }
        else if (i < 32768) { int j = i - 24576; int n = j >> 6, k = j & 63;  v = dW1[k * 128 + n]; }
        else                { int j = i - 32768; int n = j >> 6, k = j & 63;  v = dW1[(64 + k) * 128 + n]; }
        wt[i] = __float2bfloat16(v);
    }
}

// ---------------- P2: scatter edges into (bucket,chunk) ranges ----------

__global__ __launch_bounds__(256) void p2_scatter_kernel(
    const int* __restrict__ src, const int* __restrict__ dst,
    const float* __restrict__ ew, const int* __restrict__ gs,
    uint2* __restrict__ bpos, int E, int nchunks, int nb)
{
    __shared__ int cur[512];
    int c = blockIdx.x;
    for (int i = threadIdx.x; i < nb; i += 256) cur[i] = gs[i * nchunks + c];
    __syncthreads();
    int base = c * CHUNK;
    int end = min(base + CHUNK, E);
    for (int i = base + threadIdx.x; i < end; i += 256) {
        int d = dst[i];
        int pos = atomicAdd(&cur[d >> 7], 1);
        bpos[pos] = make_uint2(((unsigned)d << 16) | (unsigned)src[i],
                               __float_as_uint(ew[i]));
    }
}

// ---------------- P3: per-bucket deg/off + place edges (4B csr) ----------
// csr4 entry: (bf16 weight bits << 16) | src_u16   (RNE rounding)

__global__ __launch_bounds__(256) void p3_place_kernel(
    const uint2* __restrict__ bpos, const int* __restrict__ gs,
    int* __restrict__ deg, int* __restrict__ off,
    unsigned* __restrict__ csr4, int E, int nchunks, int nb, int N)
{
    __shared__ int cnt[128];
    __shared__ int pos[128];
    int b = blockIdx.x;
    int nodebase = b << 7;
    if (threadIdx.x < 128) cnt[threadIdx.x] = 0;
    __syncthreads();
    int begin = gs[b * nchunks];
    int bend = (b + 1 < nb) ? gs[(b + 1) * nchunks] : E;
    for (int i = begin + threadIdx.x; i < bend; i += 256)
        atomicAdd(&cnt[(bpos[i].x >> 16) - nodebase], 1);
    __syncthreads();
    int v = 0;
    if (threadIdx.x < 128) { v = cnt[threadIdx.x]; pos[threadIdx.x] = v; }
    __syncthreads();
    #pragma unroll
    for (int ofs = 1; ofs < 128; ofs <<= 1) {
        int t = 0;
        if (threadIdx.x < 128 && threadIdx.x >= ofs) t = pos[threadIdx.x - ofs];
        __syncthreads();
        if (threadIdx.x < 128) pos[threadIdx.x] += t;
        __syncthreads();
    }
    if (threadIdx.x < 128) {
        int ex = begin + pos[threadIdx.x] - v;
        int n = nodebase + threadIdx.x;
        if (n < N) { off[n] = ex; deg[n] = v; }
        cnt[threadIdx.x] = ex;
    }
    __syncthreads();
    for (int i = begin + threadIdx.x; i < bend; i += 256) {
        uint2 en = bpos[i];
        int d = en.x >> 16;
        int p = atomicAdd(&cnt[d - nodebase], 1);
        unsigned u = en.y;
        unsigned wb = (u + 0x7fffu + ((u >> 16) & 1u)) & 0xffff0000u;  // RNE to bf16
        csr4[p] = wb | (en.x & 0xffffu);
    }
}

// ---------------- scan helpers ----------------

__global__ __launch_bounds__(1024) void scan_block_kernel(
    const int* __restrict__ in, int* __restrict__ out,
    int* __restrict__ partials, int N)
{
    __shared__ int sdata[1024];
    const int tid = threadIdx.x;
    const int i = blockIdx.x * 1024 + tid;
    int v = (i < N) ? in[i] : 0;
    sdata[tid] = v;
    __syncthreads();
    #pragma unroll
    for (int ofs = 1; ofs < 1024; ofs <<= 1) {
        int t = (tid >= ofs) ? sdata[tid - ofs] : 0;
        __syncthreads();
        sdata[tid] += t;
        __syncthreads();
    }
    if (i < N) out[i] = sdata[tid] - v;
    if (partials && tid == 1023) partials[blockIdx.x] = sdata[1023];
}

__global__ __launch_bounds__(1024) void scan_add_kernel(
    int* __restrict__ off, const int* __restrict__ blockoff, int N)
{
    int i = blockIdx.x * blockDim.x + threadIdx.x;
    if (i < N) off[i] += blockoff[i >> 10];
}

// ---------------- fused layer 1: CSR gather + expand to 128 (bf16 out) ----

__global__ __launch_bounds__(256) void layer1_fused_kernel(
    const float2* __restrict__ x2, const unsigned* __restrict__ csr4,
    const int* __restrict__ off, const int* __restrict__ deg,
    const float* __restrict__ W1rel, const float* __restrict__ W1rt,
    const float* __restrict__ b1, __hip_bfloat16* __restrict__ h1b, int N)
{
    int t = blockIdx.x * blockDim.x + threadIdx.x;
    int n = t >> 6;
    if (n >= N) return;
    int lane = t & 63;
    int beg = off[n], cnt = deg[n];
    float a0 = 0.f, a1 = 0.f;
    for (int i = lane; i < cnt; i += 64) {
        unsigned c = csr4[beg + i];
        float w = bf_hi(c);
        float2 xs = x2[c & 0xffffu];
        a0 = fmaf(w, xs.x, a0);
        a1 = fmaf(w, xs.y, a1);
    }
    #pragma unroll
    for (int o = 32; o > 0; o >>= 1) {
        a0 += __shfl_xor(a0, o, 64);
        a1 += __shfl_xor(a1, o, 64);
    }
    float2 xn = x2[n];
    float v0 = b1[lane] + a0 * W1rel[lane] + a1 * W1rel[128 + lane]
             + xn.x * W1rt[lane] + xn.y * W1rt[128 + lane];
    float v1 = b1[64 + lane] + a0 * W1rel[64 + lane] + a1 * W1rel[192 + lane]
             + xn.x * W1rt[64 + lane] + xn.y * W1rt[192 + lane];
    h1b[(size_t)n * 128 + lane]      = __float2bfloat16(fmaxf(v0, 0.f));
    h1b[(size_t)n * 128 + 64 + lane] = __float2bfloat16(fmaxf(v1, 0.f));
}

// ---------------- MFMA rel GEMM: out = A @ Wt^T, bf16 out ----------------

template <int K, int NOUT>
__global__ __launch_bounds__(256) void mfma_gemm_kernel(
    const __hip_bfloat16* __restrict__ A,
    const __hip_bfloat16* __restrict__ Wt,
    __hip_bfloat16* __restrict__ outb, int M)
{
    constexpr int KF = K / 32;
    constexpr int SPW = NOUT / 64;
    const int wv = threadIdx.x >> 6;
    const int lane = threadIdx.x & 63;
    const int m = lane & 15, q = lane >> 4;
    const int row0 = blockIdx.x * 16;
    const int arow = row0 + m;

    bf16x8 af[KF];
    #pragma unroll
    for (int kf = 0; kf < KF; kf++)
        af[kf] = *(const bf16x8*)(A + (size_t)arow * K + kf * 32 + q * 8);

    #pragma unroll
    for (int s = 0; s < SPW; s++) {
        const int col = (wv * SPW + s) * 16 + m;
        f32x4 acc = {0.f, 0.f, 0.f, 0.f};
        #pragma unroll
        for (int kf = 0; kf < KF; kf++) {
            bf16x8 bf = *(const bf16x8*)(Wt + (size_t)col * K + kf * 32 + q * 8);
            acc = __builtin_amdgcn_mfma_f32_16x16x32_bf16(af[kf], bf, acc, 0, 0, 0);
        }
        #pragma unroll
        for (int r = 0; r < 4; r++) {
            int rr = row0 + q * 4 + r;
            outb[(size_t)rr * NOUT + col] = __float2bfloat16(acc[r]);
        }
    }
}

// ---------------- fused gather + root MFMA GEMM ----------------
// phase 1: per-wave CSR gather of 4 nodes into LDS agg[16][64]
// phase 2: MFMA A@Wt^T; epilogue v = acc + agg + bias (+relu / +fp32 store)
// EPI 1: relu, bf16 out.  EPI 2: no relu, fp32 out + bf16 out.

template <int K, int EPI>
__global__ __launch_bounds__(256) void mfma_root_kernel(
    const __hip_bfloat16* __restrict__ A,
    const __hip_bfloat16* __restrict__ Wt,
    const float* __restrict__ bias,
    const unsigned* __restrict__ csr4, const int* __restrict__ off,
    const int* __restrict__ deg,
    const __hip_bfloat162* __restrict__ p,
    __hip_bfloat16* __restrict__ outb, float* __restrict__ outf, int M)
{
    __shared__ float aggL[16][64];
    constexpr int KF = K / 32;
    const int wv = threadIdx.x >> 6;
    const int lane = threadIdx.x & 63;
    const int half = lane >> 5, fp = lane & 31;
    const int row0 = blockIdx.x * 16;

    // phase 1: gather (half-waves split edges by parity, shfl(32) combine)
    #pragma unroll
    for (int nn = 0; nn < 4; nn++) {
        int n = row0 + wv * 4 + nn;
        int beg = off[n], cnt = deg[n];
        float a0 = 0.f, a1 = 0.f;
        int i = half;
        for (; i + 2 < cnt; i += 4) {
            unsigned c0 = csr4[beg + i];
            unsigned c1 = csr4[beg + i + 2];
            float2 v0 = __bfloat1622float2(p[(size_t)(c0 & 0xffffu) * 32 + fp]);
            float2 v1 = __bfloat1622float2(p[(size_t)(c1 & 0xffffu) * 32 + fp]);
            float w0 = bf_hi(c0), w1 = bf_hi(c1);
            a0 = fmaf(w0, v0.x, a0); a1 = fmaf(w0, v0.y, a1);
            a0 = fmaf(w1, v1.x, a0); a1 = fmaf(w1, v1.y, a1);
        }
        for (; i < cnt; i += 2) {
            unsigned c = csr4[beg + i];
            float2 v = __bfloat1622float2(p[(size_t)(c & 0xffffu) * 32 + fp]);
            float w = bf_hi(c);
            a0 = fmaf(w, v.x, a0); a1 = fmaf(w, v.y, a1);
        }
        a0 += __shfl_xor(a0, 32, 64);
        a1 += __shfl_xor(a1, 32, 64);
        if (half == 0) {
            aggL[wv * 4 + nn][2 * fp]     = a0;
            aggL[wv * 4 + nn][2 * fp + 1] = a1;
        }
    }
    __syncthreads();

    // phase 2: MFMA (NOUT=64, SPW=1)
    const int m = lane & 15, q = lane >> 4;
    const int arow = row0 + m;
    bf16x8 af[KF];
    #pragma unroll
    for (int kf = 0; kf < KF; kf++)
        af[kf] = *(const bf16x8*)(A + (size_t)arow * K + kf * 32 + q * 8);
    const int col = wv * 16 + m;
    f32x4 acc = {0.f, 0.f, 0.f, 0.f};
    #pragma unroll
    for (int kf = 0; kf < KF; kf++) {
        bf16x8 bf = *(const bf16x8*)(Wt + (size_t)col * K + kf * 32 + q * 8);
        acc = __builtin_amdgcn_mfma_f32_16x16x32_bf16(af[kf], bf, acc, 0, 0, 0);
    }
    #pragma unroll
    for (int r = 0; r < 4; r++) {
        int rloc = q * 4 + r;
        size_t idx = (size_t)(row0 + rloc) * 64 + col;
        float v = acc[r] + aggL[rloc][col] + bias[col];
        if (EPI == 1) v = fmaxf(v, 0.f);
        if (EPI == 2) outf[idx] = v;
        outb[idx] = __float2bfloat16(v);
    }
}

// ---------------- dual decoder GEMM (Z1a and Z1b in one launch) ----------

__global__ __launch_bounds__(256) void dec_gemm_kernel(
    const __hip_bfloat16* __restrict__ A,
    const __hip_bfloat16* __restrict__ Wt0,
    const __hip_bfloat16* __restrict__ Wt1,
    __hip_bfloat16* __restrict__ out0,
    __hip_bfloat16* __restrict__ out1, int gblocks)
{
    constexpr int K = 64, KF = 2, SPW = 2;
    const int hb = (blockIdx.x >= (unsigned)gblocks) ? 1 : 0;
    const __hip_bfloat16* Wt = hb ? Wt1 : Wt0;
    __hip_bfloat16* outb = hb ? out1 : out0;
    const int wv = threadIdx.x >> 6;
    const int lane = threadIdx.x & 63;
    const int m = lane & 15, q = lane >> 4;
    const int row0 = (blockIdx.x - hb * gblocks) * 16;
    const int arow = row0 + m;

    bf16x8 af[KF];
    #pragma unroll
    for (int kf = 0; kf < KF; kf++)
        af[kf] = *(const bf16x8*)(A + (size_t)arow * K + kf * 32 + q * 8);

    #pragma unroll
    for (int s = 0; s < SPW; s++) {
        const int col = (wv * SPW + s) * 16 + m;
        f32x4 acc = {0.f, 0.f, 0.f, 0.f};
        #pragma unroll
        for (int kf = 0; kf < KF; kf++) {
            bf16x8 bf = *(const bf16x8*)(Wt + (size_t)col * K + kf * 32 + q * 8);
            acc = __builtin_amdgcn_mfma_f32_16x16x32_bf16(af[kf], bf, acc, 0, 0, 0);
        }
        #pragma unroll
        for (int r = 0; r < 4; r++) {
            int rr = row0 + q * 4 + r;
            outb[(size_t)rr * 128 + col] = __float2bfloat16(acc[r]);
        }
    }
}

// ---------------- decoder: 16-lane segment per edge, persistent ----------

__global__ __launch_bounds__(256) void decoder16_kernel(
    const int* __restrict__ src, const int* __restrict__ dst,
    const uint4* __restrict__ Za, const uint4* __restrict__ Zb,
    const float* __restrict__ db1, const float* __restrict__ dW2,
    const float* __restrict__ db2, float* __restrict__ pred,
    int Eobs, int nseg)
{
    int t = blockIdx.x * blockDim.x + threadIdx.x;
    int l = t & 15;
    int seg = t >> 4;
    float4 c1a = ((const float4*)db1)[2 * l];
    float4 c1b = ((const float4*)db1)[2 * l + 1];
    float4 w2a = ((const float4*)dW2)[2 * l];
    float4 w2b = ((const float4*)dW2)[2 * l + 1];
    float b2v = db2[0];

    for (int e = seg; e < Eobs; e += nseg) {
        int s = src[e], d = dst[e];
        uint4 ua = Za[(size_t)s * 16 + l];
        uint4 ub = Zb[(size_t)d * 16 + l];
        float acc;
        acc  = fmaxf(bf_lo(ua.x) + bf_lo(ub.x) + c1a.x, 0.f) * w2a.x;
        acc += fmaxf(bf_hi(ua.x) + bf_hi(ub.x) + c1a.y, 0.f) * w2a.y;
        acc += fmaxf(bf_lo(ua.y) + bf_lo(ub.y) + c1a.z, 0.f) * w2a.z;
        acc += fmaxf(bf_hi(ua.y) + bf_hi(ub.y) + c1a.w, 0.f) * w2a.w;
        acc += fmaxf(bf_lo(ua.z) + bf_lo(ub.z) + c1b.x, 0.f) * w2b.x;
        acc += fmaxf(bf_hi(ua.z) + bf_hi(ub.z) + c1b.y, 0.f) * w2b.y;
        acc += fmaxf(bf_lo(ua.w) + bf_lo(ub.w) + c1b.z, 0.f) * w2b.z;
        acc += fmaxf(bf_hi(ua.w) + bf_hi(ub.w) + c1b.w, 0.f) * w2b.w;
        #pragma unroll
        for (int o = 8; o > 0; o >>= 1) acc += __shfl_xor(acc, o, 64);
        if (l == 0) {
            float pv = acc + b2v;
            pred[e] = pv;
            pred[e + Eobs] = pv;
        }
    }
}

// ---------------- fallback atomic path kernels ----------------

__global__ __launch_bounds__(256) void scatter_f64_kernel(
    const int* __restrict__ src, const int* __restrict__ dst,
    const float* __restrict__ ew, const float* __restrict__ p,
    float* __restrict__ agg, int E)
{
    int t = blockIdx.x * blockDim.x + threadIdx.x;
    int e = t >> 6;
    if (e >= E) return;
    int j = t & 63;
    atomicAdd(&agg[(size_t)dst[e] * 64 + j], p[(size_t)src[e] * 64 + j] * ew[e]);
}

__global__ __launch_bounds__(256) void scatter_f2_kernel(
    const int* __restrict__ src, const int* __restrict__ dst,
    const float* __restrict__ ew, const float* __restrict__ x,
    float* __restrict__ agg, int E)
{
    int e = blockIdx.x * blockDim.x + threadIdx.x;
    if (e >= E) return;
    int s = src[e], d = dst[e];
    float w = ew[e];
    atomicAdd(&agg[d * 2 + 0], x[s * 2 + 0] * w);
    atomicAdd(&agg[d * 2 + 1], x[s * 2 + 1] * w);
}

__global__ __launch_bounds__(256) void layer1_kernel(
    const float* __restrict__ x, const float* __restrict__ agg,
    const float* __restrict__ W1rel, const float* __restrict__ W1root,
    const float* __restrict__ b1, float* __restrict__ h1, int N)
{
    int t = blockIdx.x * blockDim.x + threadIdx.x;
    if (t >= N * 128) return;
    int n = t >> 7, j = t & 127;
    float v = b1[j]
        + agg[n * 2 + 0] * W1rel[j] + agg[n * 2 + 1] * W1rel[128 + j]
        + x[n * 2 + 0] * W1root[j] + x[n * 2 + 1] * W1root[128 + j];
    h1[t] = fmaxf(v, 0.f);
}

template <int K, int NOUT, bool RELU, bool HAS_EXTRA, bool HAS_BIAS>
__global__ __launch_bounds__(256) void gemm_small(
    const float* __restrict__ in, int M,
    const float* __restrict__ W, int ldw, int woff,
    const float* __restrict__ bias,
    const float* __restrict__ extra,
    float* __restrict__ out)
{
    constexpr int CPT = NOUT / 64;
    __shared__ float sW[K * NOUT];
    __shared__ float sX[4][K];
    const int tid = threadIdx.x;
    const int lane = tid & 63;
    const int wv = tid >> 6;
    for (int idx = tid; idx < K * NOUT; idx += 256) {
        int k = idx / NOUT;
        int j = idx - k * NOUT;
        sW[idx] = W[(size_t)(k + woff) * ldw + j];
    }
    __syncthreads();
    const int ROWS = 32;
    int r0 = blockIdx.x * ROWS;
    for (int rr = wv; rr < ROWS; rr += 4) {
        int r = r0 + rr;
        if (r >= M) break;
        #pragma unroll
        for (int kk = lane; kk < K; kk += 64) sX[wv][kk] = in[(size_t)r * K + kk];
        float acc[CPT][4];
        #pragma unroll
        for (int c = 0; c < CPT; c++)
            #pragma unroll
            for (int u = 0; u < 4; u++) acc[c][u] = 0.f;
        #pragma unroll
        for (int k = 0; k < K; k += 4) {
            #pragma unroll
            for (int u = 0; u < 4; u++) {
                float xv = sX[wv][k + u];
                #pragma unroll
                for (int c = 0; c < CPT; c++)
                    acc[c][u] = fmaf(xv, sW[(k + u) * NOUT + c * 64 + lane], acc[c][u]);
            }
        }
        #pragma unroll
        for (int c = 0; c < CPT; c++) {
            float v = (acc[c][0] + acc[c][1]) + (acc[c][2] + acc[c][3]);
            int j = c * 64 + lane;
            if (HAS_EXTRA) v += extra[(size_t)r * NOUT + j];
            if (HAS_BIAS) v += bias[j];
            if (RELU) v = fmaxf(v, 0.f);
            out[(size_t)r * NOUT + j] = v;
        }
    }
}

__global__ __launch_bounds__(256) void decoder_kernel(
    const int* __restrict__ src, const int* __restrict__ dst,
    const float* __restrict__ Z1a, const float* __restrict__ Z1b,
    const float* __restrict__ db1, const float* __restrict__ dW2,
    const float* __restrict__ db2, float* __restrict__ pred, int Eobs)
{
    int t = blockIdx.x * blockDim.x + threadIdx.x;
    int e = t >> 6;
    if (e >= Eobs) return;
    int lane = threadIdx.x & 63;
    int s = src[e], d = dst[e];
    float t0 = Z1a[(size_t)s * 128 + lane] + Z1b[(size_t)d * 128 + lane] + db1[lane];
    float t1 = Z1a[(size_t)s * 128 + lane + 64] + Z1b[(size_t)d * 128 + lane + 64] + db1[lane + 64];
    t0 = fmaxf(t0, 0.f);
    t1 = fmaxf(t1, 0.f);
    float acc = t0 * dW2[lane] + t1 * dW2[lane + 64];
    #pragma unroll
    for (int off = 32; off > 0; off >>= 1) acc += __shfl_xor(acc, off, 64);
    if (lane == 0) {
        float pv = acc + db2[0];
        pred[e] = pv;
        pred[e + Eobs] = pv;
    }
}

// ---------------- launch ----------------

extern "C" void kernel_launch(void* const* d_in, const int* in_sizes, int n_in,
                              void* d_out, int out_size, void* d_ws, size_t ws_size,
                              hipStream_t stream)
{
    const float* x     = (const float*)d_in[0];
    const int*   ei    = (const int*)d_in[1];
    const float* ew    = (const float*)d_in[2];
    const float* W1rel = (const float*)d_in[4];
    const float* b1    = (const float*)d_in[5];
    const float* W1rt  = (const float*)d_in[6];
    const float* W2rel = (const float*)d_in[7];
    const float* b2    = (const float*)d_in[8];
    const float* W2rt  = (const float*)d_in[9];
    const float* W3rel = (const float*)d_in[10];
    const float* b3    = (const float*)d_in[11];
    const float* W3rt  = (const float*)d_in[12];
    const float* dW1   = (const float*)d_in[13];
    const float* db1   = (const float*)d_in[14];
    const float* dW2   = (const float*)d_in[15];
    const float* db2   = (const float*)d_in[16];

    const int E    = in_sizes[2];
    const int N    = in_sizes[0] / 2;
    const int Eobs = E / 2;
    const int* src = ei;
    const int* dst = ei + E;

    // ws regions (units = floats):
    // R0 N*64: ghist/ghist_s (build) -> zb16 (compute) | R1 N*64: h1b/Z1a
    // R2 N*32: pb16 | R3 N*32: h2b | R4 N*64: bpos (build) -> Z1b16
    // deg N | off N | par 2048 | wt 20480 floats | csr4 E ints
    float* R0   = (float*)d_ws;
    float* R1   = R0 + (size_t)N * 64;
    float* R2   = R1 + (size_t)N * 64;
    float* R3   = R2 + (size_t)N * 32;
    float* R4   = R3 + (size_t)N * 32;
    int*   deg  = (int*)(R4 + (size_t)N * 64);
    int*   off  = deg + N;
    int*   par1 = off + N;
    int*   par2 = par1 + 1024;
    float* wtf  = (float*)(par2 + 1024);           // 20480 floats = 40960 bf16
    __hip_bfloat16* wt = (__hip_bfloat16*)wtf;
    unsigned* csr4 = (unsigned*)(wtf + 20480);

    __hip_bfloat16* zb16  = (__hip_bfloat16*)R0;   // R0 free after build
    __hip_bfloat16* h1b   = (__hip_bfloat16*)R1;
    __hip_bfloat16* Z1a16 = (__hip_bfloat16*)R1;
    __hip_bfloat16* pb16  = (__hip_bfloat16*)R2;
    __hip_bfloat16* h2b   = (__hip_bfloat16*)R3;
    __hip_bfloat16* Z1b16 = (__hip_bfloat16*)R4;
    uint2* bpos  = (uint2*)R4;
    int*   ghist = (int*)R0;

    const int nb      = (N + 127) >> 7;
    const int nchunks = cdiv(E, CHUNK);
    const int M       = nb * nchunks;
    int* ghist_s = ghist + M;

    size_t need = ((size_t)N * 258 + 22528 + (size_t)E * 2) * 4;
    const bool fast = (ws_size >= need) && nb <= 512 && N <= 65535 &&
                      (N % 16 == 0) &&
                      (size_t)E * 2 <= (size_t)N * 64 &&      // bpos fits R4
                      (size_t)M * 2 <= (size_t)N * 64;        // ghists fit R0

    float* pred = (float*)d_out;
    float* z    = pred + E;

    const int nscanM = cdiv(M, 1024);
    const int gblocks = N / 16;

    __hip_bfloat16* wt2rel = wt;
    __hip_bfloat16* wt2rt  = wt + 8192;
    __hip_bfloat16* wt3rel = wt + 16384;
    __hip_bfloat16* wt3rt  = wt + 20480;
    __hip_bfloat16* wtd1a  = wt + 24576;
    __hip_bfloat16* wtd1b  = wt + 32768;

    if (fast) {
        // ---- CSR build + weight prep ----
        p1_prep_kernel<<<nchunks + 160, 256, 0, stream>>>(
            dst, ghist, E, nchunks, nb, W2rel, W2rt, W3rel, W3rt, dW1, wt);
        scan_block_kernel<<<nscanM, 1024, 0, stream>>>(ghist, ghist_s, par1, M);
        scan_block_kernel<<<1, 1024, 0, stream>>>(par1, par2, nullptr, nscanM);
        scan_add_kernel<<<cdiv(M, 1024), 1024, 0, stream>>>(ghist_s, par2, M);
        p2_scatter_kernel<<<nchunks, 256, 0, stream>>>(src, dst, ew, ghist_s, bpos, E, nchunks, nb);
        p3_place_kernel<<<nb, 256, 0, stream>>>(bpos, ghist_s, deg, off, csr4, E, nchunks, nb, N);

        // ---- layer 1 ----
        layer1_fused_kernel<<<cdiv((long long)N * 64, 256), 256, 0, stream>>>(
            (const float2*)x, csr4, off, deg, W1rel, W1rt, b1, h1b, N);

        // ---- layer 2: rel GEMM -> fused gather+root GEMM ----
        mfma_gemm_kernel<128, 64><<<gblocks, 256, 0, stream>>>(h1b, wt2rel, pb16, N);
        mfma_root_kernel<128, 1><<<gblocks, 256, 0, stream>>>(
            h1b, wt2rt, b2, csr4, off, deg, (const __hip_bfloat162*)pb16,
            h2b, nullptr, N);

        // ---- layer 3 ----
        mfma_gemm_kernel<64, 64><<<gblocks, 256, 0, stream>>>(h2b, wt3rel, pb16, N);
        mfma_root_kernel<64, 2><<<gblocks, 256, 0, stream>>>(
            h2b, wt3rt, b3, csr4, off, deg, (const __hip_bfloat162*)pb16,
            zb16, z, N);

        // ---- decoder ----
        dec_gemm_kernel<<<2 * gblocks, 256, 0, stream>>>(
            zb16, wtd1a, wtd1b, Z1a16, Z1b16, gblocks);
        int dblocks = 2048;
        if (dblocks > cdiv((long long)Eobs * 16, 256)) dblocks = cdiv((long long)Eobs * 16, 256);
        int nseg = dblocks * 16;
        decoder16_kernel<<<dblocks, 256, 0, stream>>>(
            src, dst, (const uint4*)Z1a16, (const uint4*)Z1b16,
            db1, dW2, db2, pred, Eobs, nseg);
    } else {
        // ---- fallback: atomic scatter path (fp32 throughout) ----
        float* agg  = R0;
        float* h1   = agg + (size_t)N * 64;
        float* h2   = h1 + (size_t)N * 128;
        float* pbuf = h2 + (size_t)N * 64;
        float* Z1a = h1;
        float* Z1b = h2;
        hipMemsetAsync(agg, 0, (size_t)N * 2 * sizeof(float), stream);
        scatter_f2_kernel<<<cdiv(E, 256), 256, 0, stream>>>(src, dst, ew, x, agg, E);
        layer1_kernel<<<cdiv((long long)N * 128, 256), 256, 0, stream>>>(x, agg, W1rel, W1rt, b1, h1, N);

        gemm_small<128, 64, false, false, false><<<cdiv(N, 32), 256, 0, stream>>>(
            h1, N, W2rel, 64, 0, nullptr, nullptr, pbuf);
        hipMemsetAsync(agg, 0, (size_t)N * 64 * sizeof(float), stream);
        scatter_f64_kernel<<<cdiv((long long)E * 64, 256), 256, 0, stream>>>(src, dst, ew, pbuf, agg, E);
        gemm_small<128, 64, true, true, true><<<cdiv(N, 32), 256, 0, stream>>>(
            h1, N, W2rt, 64, 0, b2, agg, h2);

        gemm_small<64, 64, false, false, false><<<cdiv(N, 32), 256, 0, stream>>>(
            h2, N, W3rel, 64, 0, nullptr, nullptr, pbuf);
        hipMemsetAsync(agg, 0, (size_t)N * 64 * sizeof(float), stream);
        scatter_f64_kernel<<<cdiv((long long)E * 64, 256), 256, 0, stream>>>(src, dst, ew, pbuf, agg, E);
        gemm_small<64, 64, false, true, true><<<cdiv(N, 32), 256, 0, stream>>>(
            h2, N, W3rt, 64, 0, b3, agg, z);

        gemm_small<64, 128, false, false, false><<<cdiv(N, 32), 256, 0, stream>>>(
            z, N, dW1, 128, 0, nullptr, nullptr, Z1a);
        gemm_small<64, 128, false, false, false><<<cdiv(N, 32), 256, 0, stream>>>(
            z, N, dW1, 128, 64, nullptr, nullptr, Z1b);
        decoder_kernel<<<cdiv((long long)Eobs * 64, 256), 256, 0, stream>>>(
            src, dst, Z1a, Z1b, db1, dW2, db2, pred, Eobs);
    }
}